// Round 1
// baseline (471.403 us; speedup 1.0000x reference)
//
#include <hip/hip_runtime.h>
#include <stdint.h>

#define LSEQ 2048
#define DMODEL 1024
#define NHEADS 16
#define HDIM 64
#define NBATCH 4

typedef __attribute__((ext_vector_type(8))) __bf16 bf16x8;
typedef __attribute__((ext_vector_type(4))) __bf16 bf16x4;
typedef __attribute__((ext_vector_type(4))) float f32x4;

// ---------------------------------------------------------------------------
// async global->LDS 16B copy (CK-style address-space casts; LDS dest is
// wave-uniform base + lane*16, global src is per-lane)
// ---------------------------------------------------------------------------
__device__ inline void gload_lds16(const void* g, const void* l) {
    auto gp = reinterpret_cast<const uint32_t __attribute__((address_space(1)))*>(
        reinterpret_cast<uintptr_t>(g));
    auto lp = reinterpret_cast<uint32_t __attribute__((address_space(3)))*>(
        (uint32_t)(uintptr_t)(l));
    __builtin_amdgcn_global_load_lds(gp, lp, 16, 0, 0);
}

// ---------------------------------------------------------------------------
// fp32 -> bf16 convert (vectorized)
// ---------------------------------------------------------------------------
__global__ void cvt_f32_bf16(const float* __restrict__ src, __bf16* __restrict__ dst, int n) {
    int idx = blockIdx.x * blockDim.x + threadIdx.x;
    int stride = gridDim.x * blockDim.x;
    for (int i = idx * 4; i < n; i += stride * 4) {
        float4 f = *(const float4*)(src + i);
        bf16x4 v;
        v[0] = (__bf16)f.x; v[1] = (__bf16)f.y; v[2] = (__bf16)f.z; v[3] = (__bf16)f.w;
        *(bf16x4*)(dst + i) = v;
    }
}

// ---------------------------------------------------------------------------
// GEMM: C[m][n] = sum_k A[m][k]*Bw[n][k] + bias[n]   (both row-major, NT)
// 128x128 tile, BK=32, 4 waves (2x2), mfma_f32_16x16x32_bf16, m97 structure.
// MODE 0: write bf16 into per-head layout [b][h][l][d]  (n = h*64+d, m = b*L+l)
// MODE 1: write fp32 row-major [m][n]
// ---------------------------------------------------------------------------
template <int MODE>
__global__ __launch_bounds__(256) void gemm_bt(const __bf16* __restrict__ A,
                                               const __bf16* __restrict__ Bw,
                                               const float* __restrict__ bias,
                                               void* __restrict__ Cout,
                                               int M, int N, int K) {
    __shared__ __bf16 As[128 * 32];
    __shared__ __bf16 Bs[128 * 32];

    const int nbn = N >> 7;
    const int bm = (blockIdx.x / nbn) << 7;
    const int bn = (blockIdx.x % nbn) << 7;
    const int tid = threadIdx.x;
    const int w = tid >> 6, lane = tid & 63;
    const int l15 = lane & 15, l4 = lane >> 4;
    const int wm = (w >> 1) * 64, wn = (w & 1) * 64;

    f32x4 acc[4][4];
    for (int i = 0; i < 4; i++)
        for (int j = 0; j < 4; j++)
            acc[i][j] = (f32x4){0.f, 0.f, 0.f, 0.f};

    // staging decomposition: 8KB per tile per matrix = 8 wave-chunks of 1KB
    const int fa0 = (w * 2 + 0) * 64 + lane;   // flat 16B-chunk index
    const int fa1 = (w * 2 + 1) * 64 + lane;
    const __bf16* gA0 = A + (size_t)(bm + (fa0 >> 2)) * K + (fa0 & 3) * 8;
    const __bf16* gA1 = A + (size_t)(bm + (fa1 >> 2)) * K + (fa1 & 3) * 8;
    const __bf16* gB0 = Bw + (size_t)(bn + (fa0 >> 2)) * K + (fa0 & 3) * 8;
    const __bf16* gB1 = Bw + (size_t)(bn + (fa1 >> 2)) * K + (fa1 & 3) * 8;
    const __bf16* lA0 = &As[(w * 2 + 0) * 512];   // wave-uniform LDS bases
    const __bf16* lA1 = &As[(w * 2 + 1) * 512];
    const __bf16* lB0 = &Bs[(w * 2 + 0) * 512];
    const __bf16* lB1 = &Bs[(w * 2 + 1) * 512];

    for (int kt = 0; kt < K; kt += 32) {
        __syncthreads();
        gload_lds16(gA0 + kt, lA0);
        gload_lds16(gA1 + kt, lA1);
        gload_lds16(gB0 + kt, lB0);
        gload_lds16(gB1 + kt, lB1);
        __syncthreads();

        bf16x8 af[4], bw[4];
        for (int i = 0; i < 4; i++)
            af[i] = *(const bf16x8*)&As[(wm + i * 16 + l15) * 32 + l4 * 8];
        for (int j = 0; j < 4; j++)
            bw[j] = *(const bf16x8*)&Bs[(wn + j * 16 + l15) * 32 + l4 * 8];
        for (int i = 0; i < 4; i++)
            for (int j = 0; j < 4; j++)
                acc[i][j] = __builtin_amdgcn_mfma_f32_16x16x32_bf16(af[i], bw[j], acc[i][j], 0, 0, 0);
    }

    // epilogue: C/D layout col = lane&15, row = (lane>>4)*4 + reg
    for (int i = 0; i < 4; i++) {
        const int row0 = bm + wm + i * 16 + l4 * 4;
        for (int j = 0; j < 4; j++) {
            const int col = bn + wn + j * 16 + l15;
            const float bv = bias[col];
            if (MODE == 0) {
                __bf16* dst = (__bf16*)Cout;
                const int h = col >> 6, d = col & 63;
                for (int jj = 0; jj < 4; jj++) {
                    const int r = row0 + jj;
                    const int b = r >> 11, l = r & (LSEQ - 1);
                    dst[(((size_t)(b * NHEADS + h) * LSEQ + l) << 6) + d] =
                        (__bf16)(acc[i][j][jj] + bv);
                }
            } else {
                float* dst = (float*)Cout;
                for (int jj = 0; jj < 4; jj++) {
                    const int r = row0 + jj;
                    dst[(size_t)r * N + col] = acc[i][j][jj] + bv;
                }
            }
        }
    }
}

// ---------------------------------------------------------------------------
// Flash attention: grid = (L/64) qtiles * 64 bh, qtile-major for mask L2 reuse.
// 4 waves x 16 Q-rows. Q in regs; K in padded LDS; V transposed in padded LDS;
// P re-laid-out through per-wave LDS for the PV MFMA.
// ---------------------------------------------------------------------------
__global__ __launch_bounds__(256) void attn_fwd(const __bf16* __restrict__ Q,
                                                const __bf16* __restrict__ Kk,
                                                const __bf16* __restrict__ V,
                                                const int* __restrict__ mask,
                                                __bf16* __restrict__ Oout) {
    const int bh = blockIdx.x & 63;
    const int qt = blockIdx.x >> 6;
    const int tid = threadIdx.x;
    const int w = tid >> 6, lane = tid & 63;
    const int l15 = lane & 15, l4 = lane >> 4;

    __shared__ __bf16 Ks[64][72];      // K rows (stride 144B: 2-way conflicts)
    __shared__ __bf16 Vt[64][72];      // V transposed: Vt[d][k]
    __shared__ __bf16 Ps[4][16][72];   // per-wave P tile

    const int q0 = qt * 64 + w * 16;
    const __bf16* qbase = Q + ((size_t)bh * LSEQ + q0 + l15) * HDIM + l4 * 8;
    const bf16x8 aq0 = *(const bf16x8*)(qbase);
    const bf16x8 aq1 = *(const bf16x8*)(qbase + 32);

    f32x4 o[4];
    for (int f = 0; f < 4; f++) o[f] = (f32x4){0.f, 0.f, 0.f, 0.f};
    float m_run[4], l_run[4];
    for (int jj = 0; jj < 4; jj++) { m_run[jj] = -3.0e38f; l_run[jj] = 0.f; }

    const int r0 = tid >> 3;          // staging row (0..31) per iteration
    const int c8 = (tid & 7) * 8;     // staging col (8-elem chunk)
    const __bf16* kg = Kk + (size_t)bh * LSEQ * HDIM;
    const __bf16* vg = V + (size_t)bh * LSEQ * HDIM;

    const int qrow_g = q0 + l4 * 4;
    const int* mrow0 = mask + (size_t)qrow_g * LSEQ;

    const float cs = 0.18033688011112f;       // 0.125 * log2(e)
    const float MASKED = -1.803368801e8f;     // -1e9 * 0.125 * log2(e)

    for (int kt = 0; kt < LSEQ; kt += 64) {
        __syncthreads();
        for (int it = 0; it < 2; it++) {
            const int r = r0 + it * 32;
            bf16x8 kv = *(const bf16x8*)(kg + (size_t)(kt + r) * HDIM + c8);
            *(bf16x8*)&Ks[r][c8] = kv;
            bf16x8 vv = *(const bf16x8*)(vg + (size_t)(kt + r) * HDIM + c8);
            for (int j = 0; j < 8; j++) Vt[c8 + j][r] = vv[j];
        }
        __syncthreads();

        // S = Q K^T  (contraction over d=64, two k-steps of 32)
        f32x4 sf[4];
        for (int f = 0; f < 4; f++) {
            bf16x8 bk0 = *(const bf16x8*)&Ks[f * 16 + l15][l4 * 8];
            bf16x8 bk1 = *(const bf16x8*)&Ks[f * 16 + l15][32 + l4 * 8];
            f32x4 z = (f32x4){0.f, 0.f, 0.f, 0.f};
            z = __builtin_amdgcn_mfma_f32_16x16x32_bf16(aq0, bk0, z, 0, 0, 0);
            z = __builtin_amdgcn_mfma_f32_16x16x32_bf16(aq1, bk1, z, 0, 0, 0);
            sf[f] = z;
        }

        // scale (folded into exp2 domain) + mask
        for (int f = 0; f < 4; f++)
            for (int jj = 0; jj < 4; jj++) {
                const int mk = mrow0[jj * LSEQ + kt + f * 16 + l15];
                const float sv = sf[f][jj] * cs;
                sf[f][jj] = mk ? sv : MASKED;
            }

        // online softmax: row stats via 16-lane butterflies
        float alpha[4];
        for (int jj = 0; jj < 4; jj++) {
            float vmx = fmaxf(fmaxf(sf[0][jj], sf[1][jj]), fmaxf(sf[2][jj], sf[3][jj]));
            vmx = fmaxf(vmx, __shfl_xor(vmx, 1));
            vmx = fmaxf(vmx, __shfl_xor(vmx, 2));
            vmx = fmaxf(vmx, __shfl_xor(vmx, 4));
            vmx = fmaxf(vmx, __shfl_xor(vmx, 8));
            const float mnew = fmaxf(m_run[jj], vmx);
            alpha[jj] = exp2f(m_run[jj] - mnew);
            m_run[jj] = mnew;
        }
        float psum[4] = {0.f, 0.f, 0.f, 0.f};
        for (int f = 0; f < 4; f++)
            for (int jj = 0; jj < 4; jj++) {
                const float p = exp2f(sf[f][jj] - m_run[jj]);
                sf[f][jj] = p;
                psum[jj] += p;
            }
        for (int jj = 0; jj < 4; jj++) {
            float s = psum[jj];
            s += __shfl_xor(s, 1);
            s += __shfl_xor(s, 2);
            s += __shfl_xor(s, 4);
            s += __shfl_xor(s, 8);
            l_run[jj] = l_run[jj] * alpha[jj] + s;
        }

        // P -> LDS (bf16), wave-local (in-order DS, no barrier needed)
        for (int f = 0; f < 4; f++)
            for (int jj = 0; jj < 4; jj++)
                Ps[w][l4 * 4 + jj][f * 16 + l15] = (__bf16)sf[f][jj];

        // rescale O
        for (int f = 0; f < 4; f++)
            for (int jj = 0; jj < 4; jj++) o[f][jj] *= alpha[jj];

        // O += P V  (contraction over k=64, two k-steps)
        const bf16x8 pa0 = *(const bf16x8*)&Ps[w][l15][l4 * 8];
        const bf16x8 pa1 = *(const bf16x8*)&Ps[w][l15][32 + l4 * 8];
        for (int f = 0; f < 4; f++) {
            bf16x8 bv0 = *(const bf16x8*)&Vt[f * 16 + l15][l4 * 8];
            bf16x8 bv1 = *(const bf16x8*)&Vt[f * 16 + l15][32 + l4 * 8];
            o[f] = __builtin_amdgcn_mfma_f32_16x16x32_bf16(pa0, bv0, o[f], 0, 0, 0);
            o[f] = __builtin_amdgcn_mfma_f32_16x16x32_bf16(pa1, bv1, o[f], 0, 0, 0);
        }
    }

    // epilogue: O /= l, write bf16 to [b][l][h*64+d]
    const int b = bh >> 4, h = bh & 15;
    for (int jj = 0; jj < 4; jj++) {
        const float inv = 1.0f / l_run[jj];
        const int l = q0 + l4 * 4 + jj;
        for (int f = 0; f < 4; f++)
            Oout[((size_t)b * LSEQ + l) * DMODEL + h * HDIM + f * 16 + l15] =
                (__bf16)(o[f][jj] * inv);
    }
}

// ---------------------------------------------------------------------------
extern "C" void kernel_launch(void* const* d_in, const int* in_sizes, int n_in,
                              void* d_out, int out_size, void* d_ws, size_t ws_size,
                              hipStream_t stream) {
    const float* x  = (const float*)d_in[0];
    const int* mask = (const int*)d_in[1];
    const float* Wq = (const float*)d_in[2];
    const float* bq = (const float*)d_in[3];
    const float* Wk = (const float*)d_in[4];
    const float* bk = (const float*)d_in[5];
    const float* Wv = (const float*)d_in[6];
    const float* bv = (const float*)d_in[7];
    const float* Wo = (const float*)d_in[8];
    const float* bo = (const float*)d_in[9];

    char* ws = (char*)d_ws;
    __bf16* xb  = (__bf16*)(ws);                    // 16 MiB  [8192][1024]
    __bf16* wqb = (__bf16*)(ws + (16u << 20));      // 2 MiB
    __bf16* wkb = (__bf16*)(ws + (18u << 20));
    __bf16* wvb = (__bf16*)(ws + (20u << 20));
    __bf16* wob = (__bf16*)(ws + (22u << 20));
    __bf16* qb  = (__bf16*)(ws + (24u << 20));      // 16 MiB  [b][h][l][64]
    __bf16* kb  = (__bf16*)(ws + (40u << 20));
    __bf16* vb  = (__bf16*)(ws + (56u << 20));
    __bf16* ab  = (__bf16*)(ws + (72u << 20));      // 16 MiB  [b][l][1024]

    const int M = NBATCH * LSEQ;   // 8192
    const int N = DMODEL;          // 1024
    const int K = DMODEL;          // 1024

    cvt_f32_bf16<<<2048, 256, 0, stream>>>(x, xb, M * K);
    cvt_f32_bf16<<<1024, 256, 0, stream>>>(Wq, wqb, N * K);
    cvt_f32_bf16<<<1024, 256, 0, stream>>>(Wk, wkb, N * K);
    cvt_f32_bf16<<<1024, 256, 0, stream>>>(Wv, wvb, N * K);
    cvt_f32_bf16<<<1024, 256, 0, stream>>>(Wo, wob, N * K);

    const int gblocks = (M / 128) * (N / 128);  // 512
    gemm_bt<0><<<gblocks, 256, 0, stream>>>(xb, wqb, bq, qb, M, N, K);
    gemm_bt<0><<<gblocks, 256, 0, stream>>>(xb, wkb, bk, kb, M, N, K);
    gemm_bt<0><<<gblocks, 256, 0, stream>>>(xb, wvb, bv, vb, M, N, K);

    attn_fwd<<<(LSEQ / 64) * 64, 256, 0, stream>>>(qb, kb, vb, mask, ab);

    gemm_bt<1><<<gblocks, 256, 0, stream>>>(ab, wob, bo, d_out, M, N, K);
}

// Round 4
// 398.824 us; speedup vs baseline: 1.1820x; 1.1820x over previous
//
#include <hip/hip_runtime.h>
#include <stdint.h>

#define LSEQ 2048
#define DMODEL 1024
#define NHEADS 16
#define HDIM 64
#define NBATCH 4

typedef __attribute__((ext_vector_type(8))) __bf16 bf16x8;
typedef __attribute__((ext_vector_type(4))) __bf16 bf16x4;
typedef __attribute__((ext_vector_type(4))) float f32x4;
typedef __attribute__((ext_vector_type(4))) uint32_t u32x4;
typedef __attribute__((ext_vector_type(8))) uint16_t u16x8;

// ---------------------------------------------------------------------------
// async global->LDS 16B copy (LDS dest = wave-uniform base + lane*16)
// ---------------------------------------------------------------------------
__device__ inline void gload_lds16(const void* g, const void* l) {
    auto gp = reinterpret_cast<const uint32_t __attribute__((address_space(1)))*>(
        reinterpret_cast<uintptr_t>(g));
    auto lp = reinterpret_cast<uint32_t __attribute__((address_space(3)))*>(
        (uint32_t)(uintptr_t)(l));
    __builtin_amdgcn_global_load_lds(gp, lp, 16, 0, 0);
}

// ---------------------------------------------------------------------------
// fp32 -> bf16 convert (vectorized)
// ---------------------------------------------------------------------------
__global__ void cvt_f32_bf16(const float* __restrict__ src, __bf16* __restrict__ dst, int n) {
    int idx = blockIdx.x * blockDim.x + threadIdx.x;
    int stride = gridDim.x * blockDim.x;
    for (int i = idx * 4; i < n; i += stride * 4) {
        float4 f = *(const float4*)(src + i);
        bf16x4 v;
        v[0] = (__bf16)f.x; v[1] = (__bf16)f.y; v[2] = (__bf16)f.z; v[3] = (__bf16)f.w;
        *(bf16x4*)(dst + i) = v;
    }
}

// ---------------------------------------------------------------------------
// mask bit-pack: int32 [2048][2048] -> uint64 [2048][32] via __ballot
// ---------------------------------------------------------------------------
__global__ void pack_mask(const int* __restrict__ mask, unsigned long long* __restrict__ mbits) {
    const int row = blockIdx.x;
    const int w = threadIdx.x >> 6, lane = threadIdx.x & 63;
    const int* mrow = mask + (size_t)row * LSEQ;
#pragma unroll
    for (int it = 0; it < 8; it++) {
        const int c = it * 256 + w * 64 + lane;
        const unsigned long long b = __ballot(mrow[c] != 0);
        if (lane == 0) mbits[(size_t)row * 32 + it * 4 + w] = b;
    }
}

// ---------------------------------------------------------------------------
// GEMM: C[m][n] = sum_k A[m][k]*Bw[n][k] + bias[n]   (both row-major, NT)
// 128x128 tile, BK=32, 4 waves (2x2), mfma_f32_16x16x32_bf16, m97 structure.
// MODE 0: bf16 into per-head layout [b][h][l][d];  MODE 1: fp32 row-major
// ---------------------------------------------------------------------------
template <int MODE>
__global__ __launch_bounds__(256) void gemm_bt(const __bf16* __restrict__ A,
                                               const __bf16* __restrict__ Bw,
                                               const float* __restrict__ bias,
                                               void* __restrict__ Cout,
                                               int M, int N, int K) {
    __shared__ __bf16 As[128 * 32];
    __shared__ __bf16 Bs[128 * 32];

    const int nbn = N >> 7;
    const int bm = (blockIdx.x / nbn) << 7;
    const int bn = (blockIdx.x % nbn) << 7;
    const int tid = threadIdx.x;
    const int w = tid >> 6, lane = tid & 63;
    const int l15 = lane & 15, l4 = lane >> 4;
    const int wm = (w >> 1) * 64, wn = (w & 1) * 64;

    f32x4 acc[4][4];
    for (int i = 0; i < 4; i++)
        for (int j = 0; j < 4; j++)
            acc[i][j] = (f32x4){0.f, 0.f, 0.f, 0.f};

    const int fa0 = (w * 2 + 0) * 64 + lane;
    const int fa1 = (w * 2 + 1) * 64 + lane;
    const __bf16* gA0 = A + (size_t)(bm + (fa0 >> 2)) * K + (fa0 & 3) * 8;
    const __bf16* gA1 = A + (size_t)(bm + (fa1 >> 2)) * K + (fa1 & 3) * 8;
    const __bf16* gB0 = Bw + (size_t)(bn + (fa0 >> 2)) * K + (fa0 & 3) * 8;
    const __bf16* gB1 = Bw + (size_t)(bn + (fa1 >> 2)) * K + (fa1 & 3) * 8;
    const __bf16* lA0 = &As[(w * 2 + 0) * 512];
    const __bf16* lA1 = &As[(w * 2 + 1) * 512];
    const __bf16* lB0 = &Bs[(w * 2 + 0) * 512];
    const __bf16* lB1 = &Bs[(w * 2 + 1) * 512];

    for (int kt = 0; kt < K; kt += 32) {
        __syncthreads();
        gload_lds16(gA0 + kt, lA0);
        gload_lds16(gA1 + kt, lA1);
        gload_lds16(gB0 + kt, lB0);
        gload_lds16(gB1 + kt, lB1);
        __syncthreads();

        bf16x8 af[4], bw[4];
        for (int i = 0; i < 4; i++)
            af[i] = *(const bf16x8*)&As[(wm + i * 16 + l15) * 32 + l4 * 8];
        for (int j = 0; j < 4; j++)
            bw[j] = *(const bf16x8*)&Bs[(wn + j * 16 + l15) * 32 + l4 * 8];
        for (int i = 0; i < 4; i++)
            for (int j = 0; j < 4; j++)
                acc[i][j] = __builtin_amdgcn_mfma_f32_16x16x32_bf16(af[i], bw[j], acc[i][j], 0, 0, 0);
    }

    for (int i = 0; i < 4; i++) {
        const int row0 = bm + wm + i * 16 + l4 * 4;
        for (int j = 0; j < 4; j++) {
            const int col = bn + wn + j * 16 + l15;
            const float bv = bias[col];
            if (MODE == 0) {
                __bf16* dst = (__bf16*)Cout;
                const int h = col >> 6, d = col & 63;
                for (int jj = 0; jj < 4; jj++) {
                    const int r = row0 + jj;
                    const int b = r >> 11, l = r & (LSEQ - 1);
                    dst[(((size_t)(b * NHEADS + h) * LSEQ + l) << 6) + d] =
                        (__bf16)(acc[i][j][jj] + bv);
                }
            } else {
                float* dst = (float*)Cout;
                for (int jj = 0; jj < 4; jj++) {
                    const int r = row0 + jj;
                    dst[(size_t)r * N + col] = acc[i][j][jj] + bv;
                }
            }
        }
    }
}

// ---------------------------------------------------------------------------
// Flash attention. grid = 32 qtiles x 64 bh (bh minor). 4 waves x 16 Q-rows.
// K: linear LDS via gload_lds, 16B-chunk XOR swizzle (^row&7) applied to the
//    GLOBAL source address; same XOR on the fragment read (T2 / rule 21).
// V: reg-staged into k-pair transposed layout  uint32 Vt32[d][kp] =
//    (V[2kp][d] lo16, V[2kp+1][d] hi16), 4-word-block XOR swizzle (blk^=d&7).
//    PV B-fragment = one aligned u32x4 read. No HW-transpose instruction.
// Mask: bit-packed uint64 words. Ps pad=72 (144B rows, 16B-aligned).
// ---------------------------------------------------------------------------
__global__ __launch_bounds__(256) void attn_fwd(const __bf16* __restrict__ Q,
                                                const __bf16* __restrict__ Kk,
                                                const __bf16* __restrict__ V,
                                                const unsigned long long* __restrict__ mbits,
                                                __bf16* __restrict__ Oout) {
    const int bh = blockIdx.x & 63;
    const int qt = blockIdx.x >> 6;
    const int tid = threadIdx.x;
    const int w = tid >> 6, lane = tid & 63;
    const int l15 = lane & 15, l4 = lane >> 4, l7 = l15 & 7;

    __shared__ __bf16 Ks[64 * 64];       // row-major, 16B-chunk XOR swizzle
    __shared__ uint32_t Vt32[64][32];    // [d][kpair], block-XOR swizzled
    __shared__ __bf16 Ps[4][16][72];     // per-wave P tile; 144B rows

    const int q0 = qt * 64 + w * 16;
    const __bf16* qbase = Q + ((size_t)bh * LSEQ + q0 + l15) * HDIM + l4 * 8;
    const bf16x8 aq0 = *(const bf16x8*)(qbase);
    const bf16x8 aq1 = *(const bf16x8*)(qbase + 32);

    f32x4 o[4];
    for (int f = 0; f < 4; f++) o[f] = (f32x4){0.f, 0.f, 0.f, 0.f};
    float m_run[4], l_run[4];
    for (int jj = 0; jj < 4; jj++) { m_run[jj] = -3.0e38f; l_run[jj] = 0.f; }

    // ---- K staging (16B chunks; 512 chunks per 8KB tile) ----
    const int ck0 = w * 64 + lane;
    const int ck1 = ck0 + 256;
    const int koff0 = ((ck0 >> 3) << 7) + ((((ck0 & 7) ^ ((ck0 >> 3) & 7))) << 4);
    const int koff1 = ((ck1 >> 3) << 7) + ((((ck1 & 7) ^ ((ck1 >> 3) & 7))) << 4);
    const char* kgb = (const char*)(Kk + (size_t)bh * LSEQ * HDIM);
    const __bf16* vg = V + (size_t)bh * LSEQ * HDIM;
    __bf16* ldsK0 = &Ks[w * 512];
    __bf16* ldsK1 = &Ks[w * 512 + 2048];

    // K fragment read (byte) addrs: row*128 + 16*((ks*4+l4)^l7), row = f*16+l15
    const int kread0 = l15 * 128 + ((l4 ^ l7) << 4);
    const int kread1 = l15 * 128 + (((4 + l4) ^ l7) << 4);
    // V fragment read (word) addrs: row*32 + 4*((ks*4+l4)^l7), row = f*16+l15
    const int vread0 = l15 * 32 + ((l4 ^ l7) << 2);
    const int vread1 = l15 * 32 + (((4 + l4) ^ l7) << 2);
    const uint32_t* vbase = &Vt32[0][0];

    // V staging: thread -> k-pair kp (rows 2kp,2kp+1), d-chunk d0..d0+7
    const int kp = tid & 31;
    const int d0 = (tid >> 5) * 8;

    const unsigned long long* mrow = mbits + (size_t)(q0 + l4 * 4) * 32;

    const float cs = 0.18033688011112f;       // 0.125 * log2(e)
    const float MASKED = -1.803368801e8f;     // -1e9 * cs

    for (int kt = 0; kt < LSEQ; kt += 64) {
        // V tile -> regs (global only; issued before the barrier)
        const u16x8 vr0 = *(const u16x8*)(vg + (size_t)(kt + 2 * kp) * HDIM + d0);
        const u16x8 vr1 = *(const u16x8*)(vg + (size_t)(kt + 2 * kp + 1) * HDIM + d0);

        __syncthreads();   // all waves done reading prev tile's Ks/Vt32

        const size_t gb = (size_t)kt * 128;
        gload_lds16(kgb + gb + koff0, ldsK0);
        gload_lds16(kgb + gb + koff1, ldsK1);

        // mask words (L2-resident broadcast loads), pre-shifted by lane col
        const int wi = kt >> 6;
        unsigned long long msh[4];
#pragma unroll
        for (int jj = 0; jj < 4; jj++) msh[jj] = mrow[jj * 32 + wi] >> l15;

        // V regs -> LDS transposed-pair layout (d&7 == j since d0 % 8 == 0)
#pragma unroll
        for (int j = 0; j < 8; j++)
            Vt32[d0 + j][(kp & 3) | (((kp >> 2) ^ j) << 2)] =
                (uint32_t)vr0[j] | ((uint32_t)vr1[j] << 16);

        __syncthreads();

        // ---- S = Q K^T ----
        f32x4 sf[4];
#pragma unroll
        for (int f = 0; f < 4; f++) {
            const bf16x8 bk0 = *(const bf16x8*)((const char*)Ks + f * 2048 + kread0);
            const bf16x8 bk1 = *(const bf16x8*)((const char*)Ks + f * 2048 + kread1);
            f32x4 z = (f32x4){0.f, 0.f, 0.f, 0.f};
            z = __builtin_amdgcn_mfma_f32_16x16x32_bf16(aq0, bk0, z, 0, 0, 0);
            z = __builtin_amdgcn_mfma_f32_16x16x32_bf16(aq1, bk1, z, 0, 0, 0);
            sf[f] = z;
        }

        // ---- scale + mask (bit test) ----
#pragma unroll
        for (int f = 0; f < 4; f++)
#pragma unroll
            for (int jj = 0; jj < 4; jj++) {
                const float sv = sf[f][jj] * cs;
                sf[f][jj] = ((msh[jj] >> (f * 16)) & 1ull) ? sv : MASKED;
            }

        // ---- online softmax (16-lane butterflies) ----
        float alpha[4];
#pragma unroll
        for (int jj = 0; jj < 4; jj++) {
            float vmx = fmaxf(fmaxf(sf[0][jj], sf[1][jj]), fmaxf(sf[2][jj], sf[3][jj]));
            vmx = fmaxf(vmx, __shfl_xor(vmx, 1));
            vmx = fmaxf(vmx, __shfl_xor(vmx, 2));
            vmx = fmaxf(vmx, __shfl_xor(vmx, 4));
            vmx = fmaxf(vmx, __shfl_xor(vmx, 8));
            const float mnew = fmaxf(m_run[jj], vmx);
            alpha[jj] = exp2f(m_run[jj] - mnew);
            m_run[jj] = mnew;
        }
        float psum[4] = {0.f, 0.f, 0.f, 0.f};
#pragma unroll
        for (int f = 0; f < 4; f++)
#pragma unroll
            for (int jj = 0; jj < 4; jj++) {
                const float p = exp2f(sf[f][jj] - m_run[jj]);
                sf[f][jj] = p;
                psum[jj] += p;
            }
#pragma unroll
        for (int jj = 0; jj < 4; jj++) {
            float s = psum[jj];
            s += __shfl_xor(s, 1);
            s += __shfl_xor(s, 2);
            s += __shfl_xor(s, 4);
            s += __shfl_xor(s, 8);
            l_run[jj] = l_run[jj] * alpha[jj] + s;
        }

        // ---- P -> LDS (wave-local, in-order DS) ----
#pragma unroll
        for (int f = 0; f < 4; f++)
#pragma unroll
            for (int jj = 0; jj < 4; jj++)
                Ps[w][l4 * 4 + jj][f * 16 + l15] = (__bf16)sf[f][jj];
        __builtin_amdgcn_sched_barrier(0);
        const bf16x8 pa0 = *(const bf16x8*)&Ps[w][l15][l4 * 8];
        const bf16x8 pa1 = *(const bf16x8*)&Ps[w][l15][32 + l4 * 8];

        // ---- rescale O ----
#pragma unroll
        for (int f = 0; f < 4; f++)
#pragma unroll
            for (int jj = 0; jj < 4; jj++) o[f][jj] *= alpha[jj];

        // ---- O += P V ----
#pragma unroll
        for (int f = 0; f < 4; f++) {
            const bf16x8 bv0 = __builtin_bit_cast(bf16x8, *(const u32x4*)(vbase + f * 512 + vread0));
            const bf16x8 bv1 = __builtin_bit_cast(bf16x8, *(const u32x4*)(vbase + f * 512 + vread1));
            o[f] = __builtin_amdgcn_mfma_f32_16x16x32_bf16(pa0, bv0, o[f], 0, 0, 0);
            o[f] = __builtin_amdgcn_mfma_f32_16x16x32_bf16(pa1, bv1, o[f], 0, 0, 0);
        }
    }

    // epilogue: O /= l, write bf16 to [b][l][h*64+d]
    const int b = bh >> 4, h = bh & 15;
#pragma unroll
    for (int jj = 0; jj < 4; jj++) {
        const float inv = 1.0f / l_run[jj];
        const int l = q0 + l4 * 4 + jj;
#pragma unroll
        for (int f = 0; f < 4; f++)
            Oout[((size_t)b * LSEQ + l) * DMODEL + h * HDIM + f * 16 + l15] =
                (__bf16)(o[f][jj] * inv);
    }
}

// ---------------------------------------------------------------------------
extern "C" void kernel_launch(void* const* d_in, const int* in_sizes, int n_in,
                              void* d_out, int out_size, void* d_ws, size_t ws_size,
                              hipStream_t stream) {
    const float* x  = (const float*)d_in[0];
    const int* mask = (const int*)d_in[1];
    const float* Wq = (const float*)d_in[2];
    const float* bq = (const float*)d_in[3];
    const float* Wk = (const float*)d_in[4];
    const float* bk = (const float*)d_in[5];
    const float* Wv = (const float*)d_in[6];
    const float* bv = (const float*)d_in[7];
    const float* Wo = (const float*)d_in[8];
    const float* bo = (const float*)d_in[9];

    char* ws = (char*)d_ws;
    __bf16* xb  = (__bf16*)(ws);                    // 16 MiB  [8192][1024]
    __bf16* wqb = (__bf16*)(ws + (16u << 20));      // 2 MiB
    __bf16* wkb = (__bf16*)(ws + (18u << 20));
    __bf16* wvb = (__bf16*)(ws + (20u << 20));
    __bf16* wob = (__bf16*)(ws + (22u << 20));
    __bf16* qb  = (__bf16*)(ws + (24u << 20));      // 16 MiB  [b][h][l][64]
    __bf16* kb  = (__bf16*)(ws + (40u << 20));
    __bf16* vb  = (__bf16*)(ws + (56u << 20));
    __bf16* ab  = (__bf16*)(ws + (72u << 20));      // 16 MiB  [b][l][1024]
    unsigned long long* mb = (unsigned long long*)(ws + (88u << 20));  // 512 KiB

    const int M = NBATCH * LSEQ;   // 8192
    const int N = DMODEL;          // 1024
    const int K = DMODEL;          // 1024

    cvt_f32_bf16<<<2048, 256, 0, stream>>>(x, xb, M * K);
    cvt_f32_bf16<<<1024, 256, 0, stream>>>(Wq, wqb, N * K);
    cvt_f32_bf16<<<1024, 256, 0, stream>>>(Wk, wkb, N * K);
    cvt_f32_bf16<<<1024, 256, 0, stream>>>(Wv, wvb, N * K);
    cvt_f32_bf16<<<1024, 256, 0, stream>>>(Wo, wob, N * K);
    pack_mask<<<LSEQ, 256, 0, stream>>>(mask, mb);

    const int gblocks = (M / 128) * (N / 128);  // 512
    gemm_bt<0><<<gblocks, 256, 0, stream>>>(xb, wqb, bq, qb, M, N, K);
    gemm_bt<0><<<gblocks, 256, 0, stream>>>(xb, wkb, bk, kb, M, N, K);
    gemm_bt<0><<<gblocks, 256, 0, stream>>>(xb, wvb, bv, vb, M, N, K);

    attn_fwd<<<(LSEQ / 64) * 64, 256, 0, stream>>>(qb, kb, vb, mb, ab);

    gemm_bt<1><<<gblocks, 256, 0, stream>>>(ab, wob, bo, d_out, M, N, K);
}

// Round 5
// 353.222 us; speedup vs baseline: 1.3346x; 1.1291x over previous
//
#include <hip/hip_runtime.h>
#include <stdint.h>

#define LSEQ 2048
#define DMODEL 1024
#define NHEADS 16
#define HDIM 64
#define NBATCH 4

typedef __attribute__((ext_vector_type(8))) __bf16 bf16x8;
typedef __attribute__((ext_vector_type(4))) __bf16 bf16x4;
typedef __attribute__((ext_vector_type(4))) float f32x4;
typedef __attribute__((ext_vector_type(4))) uint32_t u32x4;
typedef __attribute__((ext_vector_type(8))) uint16_t u16x8;

// ---------------------------------------------------------------------------
// async global->LDS 16B copy (LDS dest = wave-uniform base + lane*16)
// ---------------------------------------------------------------------------
__device__ inline void gload_lds16(const void* g, const void* l) {
    auto gp = reinterpret_cast<const uint32_t __attribute__((address_space(1)))*>(
        reinterpret_cast<uintptr_t>(g));
    auto lp = reinterpret_cast<uint32_t __attribute__((address_space(3)))*>(
        (uint32_t)(uintptr_t)(l));
    __builtin_amdgcn_global_load_lds(gp, lp, 16, 0, 0);
}

// ---------------------------------------------------------------------------
// fp32 -> bf16 convert (vectorized)
// ---------------------------------------------------------------------------
__global__ void cvt_f32_bf16(const float* __restrict__ src, __bf16* __restrict__ dst, int n) {
    int idx = blockIdx.x * blockDim.x + threadIdx.x;
    int stride = gridDim.x * blockDim.x;
    for (int i = idx * 4; i < n; i += stride * 4) {
        float4 f = *(const float4*)(src + i);
        bf16x4 v;
        v[0] = (__bf16)f.x; v[1] = (__bf16)f.y; v[2] = (__bf16)f.z; v[3] = (__bf16)f.w;
        *(bf16x4*)(dst + i) = v;
    }
}

// ---------------------------------------------------------------------------
// mask bit-pack: int32 [2048][2048] -> uint64 [2048][32] via __ballot
// ---------------------------------------------------------------------------
__global__ void pack_mask(const int* __restrict__ mask, unsigned long long* __restrict__ mbits) {
    const int row = blockIdx.x;
    const int w = threadIdx.x >> 6, lane = threadIdx.x & 63;
    const int* mrow = mask + (size_t)row * LSEQ;
#pragma unroll
    for (int it = 0; it < 8; it++) {
        const int c = it * 256 + w * 64 + lane;
        const unsigned long long b = __ballot(mrow[c] != 0);
        if (lane == 0) mbits[(size_t)row * 32 + it * 4 + w] = b;
    }
}

// ---------------------------------------------------------------------------
// GEMM: C[m][n] = sum_k A[m][k]*Bw[n][k] + bias[n]   (both row-major, NT)
// 128x128 tile, BK=32, 4 waves (2x2), mfma_f32_16x16x32_bf16, m97 structure.
// MODE 0: bf16*(scale) into per-head layout [b][h][l][d];  MODE 1: fp32 row-major
// ---------------------------------------------------------------------------
template <int MODE>
__global__ __launch_bounds__(256) void gemm_bt(const __bf16* __restrict__ A,
                                               const __bf16* __restrict__ Bw,
                                               const float* __restrict__ bias,
                                               void* __restrict__ Cout,
                                               int M, int N, int K, float scale) {
    __shared__ __bf16 As[128 * 32];
    __shared__ __bf16 Bs[128 * 32];

    const int nbn = N >> 7;
    const int bm = (blockIdx.x / nbn) << 7;
    const int bn = (blockIdx.x % nbn) << 7;
    const int tid = threadIdx.x;
    const int w = tid >> 6, lane = tid & 63;
    const int l15 = lane & 15, l4 = lane >> 4;
    const int wm = (w >> 1) * 64, wn = (w & 1) * 64;

    f32x4 acc[4][4];
    for (int i = 0; i < 4; i++)
        for (int j = 0; j < 4; j++)
            acc[i][j] = (f32x4){0.f, 0.f, 0.f, 0.f};

    const int fa0 = (w * 2 + 0) * 64 + lane;
    const int fa1 = (w * 2 + 1) * 64 + lane;
    const __bf16* gA0 = A + (size_t)(bm + (fa0 >> 2)) * K + (fa0 & 3) * 8;
    const __bf16* gA1 = A + (size_t)(bm + (fa1 >> 2)) * K + (fa1 & 3) * 8;
    const __bf16* gB0 = Bw + (size_t)(bn + (fa0 >> 2)) * K + (fa0 & 3) * 8;
    const __bf16* gB1 = Bw + (size_t)(bn + (fa1 >> 2)) * K + (fa1 & 3) * 8;
    const __bf16* lA0 = &As[(w * 2 + 0) * 512];
    const __bf16* lA1 = &As[(w * 2 + 1) * 512];
    const __bf16* lB0 = &Bs[(w * 2 + 0) * 512];
    const __bf16* lB1 = &Bs[(w * 2 + 1) * 512];

    for (int kt = 0; kt < K; kt += 32) {
        __syncthreads();
        gload_lds16(gA0 + kt, lA0);
        gload_lds16(gA1 + kt, lA1);
        gload_lds16(gB0 + kt, lB0);
        gload_lds16(gB1 + kt, lB1);
        __syncthreads();

        bf16x8 af[4], bw[4];
        for (int i = 0; i < 4; i++)
            af[i] = *(const bf16x8*)&As[(wm + i * 16 + l15) * 32 + l4 * 8];
        for (int j = 0; j < 4; j++)
            bw[j] = *(const bf16x8*)&Bs[(wn + j * 16 + l15) * 32 + l4 * 8];
        for (int i = 0; i < 4; i++)
            for (int j = 0; j < 4; j++)
                acc[i][j] = __builtin_amdgcn_mfma_f32_16x16x32_bf16(af[i], bw[j], acc[i][j], 0, 0, 0);
    }

    for (int i = 0; i < 4; i++) {
        const int row0 = bm + wm + i * 16 + l4 * 4;
        for (int j = 0; j < 4; j++) {
            const int col = bn + wn + j * 16 + l15;
            const float bv = bias[col];
            if (MODE == 0) {
                __bf16* dst = (__bf16*)Cout;
                const int h = col >> 6, d = col & 63;
                for (int jj = 0; jj < 4; jj++) {
                    const int r = row0 + jj;
                    const int b = r >> 11, l = r & (LSEQ - 1);
                    dst[(((size_t)(b * NHEADS + h) * LSEQ + l) << 6) + d] =
                        (__bf16)((acc[i][j][jj] + bv) * scale);
                }
            } else {
                float* dst = (float*)Cout;
                for (int jj = 0; jj < 4; jj++) {
                    const int r = row0 + jj;
                    dst[(size_t)r * N + col] = acc[i][j][jj] + bv;
                }
            }
        }
    }
}

// ---------------------------------------------------------------------------
// Flash attention. grid = 32 qtiles x 64 bh (bh minor). 4 waves x 16 Q-rows.
// Q pre-scaled by 0.125*log2e in the Q-projection epilogue (scores are
// directly in exp2 domain). Row max taken over ALL columns (masked included
// — shift-invariance makes this exact); masked P zeroed after exp2, before
// psum/PV. Defer-max (thr=8) skips alpha/rescale on most tiles. Cross-lane
// l_run reduction deferred to the epilogue (per-lane partials are uniformly
// scaled since alpha/m are group-uniform after the max butterfly).
// ---------------------------------------------------------------------------
__global__ __launch_bounds__(256) void attn_fwd(const __bf16* __restrict__ Q,
                                                const __bf16* __restrict__ Kk,
                                                const __bf16* __restrict__ V,
                                                const unsigned long long* __restrict__ mbits,
                                                __bf16* __restrict__ Oout) {
    const int bh = blockIdx.x & 63;
    const int qt = blockIdx.x >> 6;
    const int tid = threadIdx.x;
    const int w = tid >> 6, lane = tid & 63;
    const int l15 = lane & 15, l4 = lane >> 4, l7 = l15 & 7;

    __shared__ __bf16 Ks[64 * 64];       // row-major, 16B-chunk XOR swizzle
    __shared__ uint32_t Vt32[64][32];    // [d][kpair], block-XOR swizzled
    __shared__ __bf16 Ps[4][16][72];     // per-wave P tile; 144B rows

    const int q0 = qt * 64 + w * 16;
    const __bf16* qbase = Q + ((size_t)bh * LSEQ + q0 + l15) * HDIM + l4 * 8;
    const bf16x8 aq0 = *(const bf16x8*)(qbase);
    const bf16x8 aq1 = *(const bf16x8*)(qbase + 32);

    f32x4 o[4];
    for (int f = 0; f < 4; f++) o[f] = (f32x4){0.f, 0.f, 0.f, 0.f};
    float m_run[4], l_run[4];
    for (int jj = 0; jj < 4; jj++) { m_run[jj] = -1.0e30f; l_run[jj] = 0.f; }

    // ---- K staging (16B chunks; 512 chunks per 8KB tile) ----
    const int ck0 = w * 64 + lane;
    const int ck1 = ck0 + 256;
    const int koff0 = ((ck0 >> 3) << 7) + ((((ck0 & 7) ^ ((ck0 >> 3) & 7))) << 4);
    const int koff1 = ((ck1 >> 3) << 7) + ((((ck1 & 7) ^ ((ck1 >> 3) & 7))) << 4);
    const char* kgb = (const char*)(Kk + (size_t)bh * LSEQ * HDIM);
    const __bf16* vg = V + (size_t)bh * LSEQ * HDIM;
    __bf16* ldsK0 = &Ks[w * 512];
    __bf16* ldsK1 = &Ks[w * 512 + 2048];

    // K fragment read (byte) addrs: row*128 + 16*((ks*4+l4)^l7), row = f*16+l15
    const int kread0 = l15 * 128 + ((l4 ^ l7) << 4);
    const int kread1 = l15 * 128 + (((4 + l4) ^ l7) << 4);
    // V fragment read (word) addrs: row*32 + 4*((ks*4+l4)^l7), row = f*16+l15
    const int vread0 = l15 * 32 + ((l4 ^ l7) << 2);
    const int vread1 = l15 * 32 + (((4 + l4) ^ l7) << 2);
    const uint32_t* vbase = &Vt32[0][0];

    // V staging: thread -> k-pair kp (rows 2kp,2kp+1), d-chunk d0..d0+7
    const int kp = tid & 31;
    const int d0 = (tid >> 5) * 8;

    const unsigned long long* mrow = mbits + (size_t)(q0 + l4 * 4) * 32;

    for (int kt = 0; kt < LSEQ; kt += 64) {
        // V tile -> regs (global only; issued before the barrier)
        const u16x8 vr0 = *(const u16x8*)(vg + (size_t)(kt + 2 * kp) * HDIM + d0);
        const u16x8 vr1 = *(const u16x8*)(vg + (size_t)(kt + 2 * kp + 1) * HDIM + d0);

        __syncthreads();   // all waves done reading prev tile's Ks/Vt32

        const size_t gb = (size_t)kt * 128;
        gload_lds16(kgb + gb + koff0, ldsK0);
        gload_lds16(kgb + gb + koff1, ldsK1);

        // mask words (L2-resident), pre-shifted so lane's bit sits at f*16
        const int wi = kt >> 6;
        unsigned long long msh[4];
#pragma unroll
        for (int jj = 0; jj < 4; jj++) msh[jj] = mrow[jj * 32 + wi] >> l15;

        // V regs -> LDS transposed-pair layout via v_perm (2 words per u32 pair)
        {
            const uint32_t* a = (const uint32_t*)&vr0;
            const uint32_t* b = (const uint32_t*)&vr1;
#pragma unroll
            for (int jp = 0; jp < 4; jp++) {
                const uint32_t w0 = __builtin_amdgcn_perm(b[jp], a[jp], 0x05040100u);
                const uint32_t w1 = __builtin_amdgcn_perm(b[jp], a[jp], 0x07060302u);
                const int j0 = jp * 2, j1 = jp * 2 + 1;
                Vt32[d0 + j0][(kp & 3) | (((kp >> 2) ^ j0) << 2)] = w0;
                Vt32[d0 + j1][(kp & 3) | (((kp >> 2) ^ j1) << 2)] = w1;
            }
        }

        __syncthreads();

        // ---- S = Q K^T (already in exp2 domain; Q pre-scaled) ----
        f32x4 sf[4];
        __builtin_amdgcn_s_setprio(1);
#pragma unroll
        for (int f = 0; f < 4; f++) {
            const bf16x8 bk0 = *(const bf16x8*)((const char*)Ks + f * 2048 + kread0);
            const bf16x8 bk1 = *(const bf16x8*)((const char*)Ks + f * 2048 + kread1);
            f32x4 z = (f32x4){0.f, 0.f, 0.f, 0.f};
            z = __builtin_amdgcn_mfma_f32_16x16x32_bf16(aq0, bk0, z, 0, 0, 0);
            z = __builtin_amdgcn_mfma_f32_16x16x32_bf16(aq1, bk1, z, 0, 0, 0);
            sf[f] = z;
        }
        __builtin_amdgcn_s_setprio(0);

        // ---- row max over ALL columns (masked included — exact) ----
        float vmx[4];
#pragma unroll
        for (int jj = 0; jj < 4; jj++) {
            float v = fmaxf(fmaxf(sf[0][jj], sf[1][jj]), fmaxf(sf[2][jj], sf[3][jj]));
            v = fmaxf(v, __shfl_xor(v, 1));
            v = fmaxf(v, __shfl_xor(v, 2));
            v = fmaxf(v, __shfl_xor(v, 4));
            v = fmaxf(v, __shfl_xor(v, 8));
            vmx[jj] = v;
        }

        // ---- defer-max: rescale only when max grew by > 8 octaves ----
        bool need = false;
#pragma unroll
        for (int jj = 0; jj < 4; jj++) need |= (vmx[jj] > m_run[jj] + 8.f);
        if (__any(need)) {
#pragma unroll
            for (int jj = 0; jj < 4; jj++) {
                const float mnew = fmaxf(m_run[jj], vmx[jj]);
                const float alpha = exp2f(m_run[jj] - mnew);
                m_run[jj] = mnew;
                l_run[jj] *= alpha;
#pragma unroll
                for (int f = 0; f < 4; f++) o[f][jj] *= alpha;
            }
        }

        // ---- P = exp2(S - m); zero masked; accumulate per-lane l partials;
        //      convert + write to per-wave LDS P tile ----
        float psum[4];
#pragma unroll
        for (int jj = 0; jj < 4; jj++) {
            const uint32_t lo = (uint32_t)msh[jj];
            const uint32_t hi = (uint32_t)(msh[jj] >> 32);
            float p0 = exp2f(sf[0][jj] - m_run[jj]);
            float p1 = exp2f(sf[1][jj] - m_run[jj]);
            float p2 = exp2f(sf[2][jj] - m_run[jj]);
            float p3 = exp2f(sf[3][jj] - m_run[jj]);
            p0 = (lo & 1u) ? p0 : 0.f;
            p1 = ((lo >> 16) & 1u) ? p1 : 0.f;
            p2 = (hi & 1u) ? p2 : 0.f;
            p3 = ((hi >> 16) & 1u) ? p3 : 0.f;
            Ps[w][l4 * 4 + jj][0 * 16 + l15] = (__bf16)p0;
            Ps[w][l4 * 4 + jj][1 * 16 + l15] = (__bf16)p1;
            Ps[w][l4 * 4 + jj][2 * 16 + l15] = (__bf16)p2;
            Ps[w][l4 * 4 + jj][3 * 16 + l15] = (__bf16)p3;
            psum[jj] = (p0 + p1) + (p2 + p3);
        }
#pragma unroll
        for (int jj = 0; jj < 4; jj++) l_run[jj] += psum[jj];

        __builtin_amdgcn_sched_barrier(0);
        const bf16x8 pa0 = *(const bf16x8*)&Ps[w][l15][l4 * 8];
        const bf16x8 pa1 = *(const bf16x8*)&Ps[w][l15][32 + l4 * 8];

        // ---- O += P V ----
        __builtin_amdgcn_s_setprio(1);
#pragma unroll
        for (int f = 0; f < 4; f++) {
            const bf16x8 bv0 = __builtin_bit_cast(bf16x8, *(const u32x4*)(vbase + f * 512 + vread0));
            const bf16x8 bv1 = __builtin_bit_cast(bf16x8, *(const u32x4*)(vbase + f * 512 + vread1));
            o[f] = __builtin_amdgcn_mfma_f32_16x16x32_bf16(pa0, bv0, o[f], 0, 0, 0);
            o[f] = __builtin_amdgcn_mfma_f32_16x16x32_bf16(pa1, bv1, o[f], 0, 0, 0);
        }
        __builtin_amdgcn_s_setprio(0);
    }

    // epilogue: cross-lane l reduction (deferred), O /= l, write bf16
    const int b = bh >> 4, h = bh & 15;
#pragma unroll
    for (int jj = 0; jj < 4; jj++) {
        float s = l_run[jj];
        s += __shfl_xor(s, 1);
        s += __shfl_xor(s, 2);
        s += __shfl_xor(s, 4);
        s += __shfl_xor(s, 8);
        const float inv = 1.0f / fmaxf(s, 1e-30f);
        const int l = q0 + l4 * 4 + jj;
#pragma unroll
        for (int f = 0; f < 4; f++)
            Oout[((size_t)b * LSEQ + l) * DMODEL + h * HDIM + f * 16 + l15] =
                (__bf16)(o[f][jj] * inv);
    }
}

// ---------------------------------------------------------------------------
extern "C" void kernel_launch(void* const* d_in, const int* in_sizes, int n_in,
                              void* d_out, int out_size, void* d_ws, size_t ws_size,
                              hipStream_t stream) {
    const float* x  = (const float*)d_in[0];
    const int* mask = (const int*)d_in[1];
    const float* Wq = (const float*)d_in[2];
    const float* bq = (const float*)d_in[3];
    const float* Wk = (const float*)d_in[4];
    const float* bk = (const float*)d_in[5];
    const float* Wv = (const float*)d_in[6];
    const float* bv = (const float*)d_in[7];
    const float* Wo = (const float*)d_in[8];
    const float* bo = (const float*)d_in[9];

    char* ws = (char*)d_ws;
    __bf16* xb  = (__bf16*)(ws);                    // 16 MiB  [8192][1024]
    __bf16* wqb = (__bf16*)(ws + (16u << 20));      // 2 MiB
    __bf16* wkb = (__bf16*)(ws + (18u << 20));
    __bf16* wvb = (__bf16*)(ws + (20u << 20));
    __bf16* wob = (__bf16*)(ws + (22u << 20));
    __bf16* qb  = (__bf16*)(ws + (24u << 20));      // 16 MiB  [b][h][l][64]
    __bf16* kb  = (__bf16*)(ws + (40u << 20));
    __bf16* vb  = (__bf16*)(ws + (56u << 20));
    __bf16* ab  = (__bf16*)(ws + (72u << 20));      // 16 MiB  [b][l][1024]
    unsigned long long* mb = (unsigned long long*)(ws + (88u << 20));  // 512 KiB

    const int M = NBATCH * LSEQ;   // 8192
    const int N = DMODEL;          // 1024
    const int K = DMODEL;          // 1024
    const float cs = 0.18033688011112f;   // 0.125 * log2(e), folded into Q

    cvt_f32_bf16<<<2048, 256, 0, stream>>>(x, xb, M * K);
    cvt_f32_bf16<<<1024, 256, 0, stream>>>(Wq, wqb, N * K);
    cvt_f32_bf16<<<1024, 256, 0, stream>>>(Wk, wkb, N * K);
    cvt_f32_bf16<<<1024, 256, 0, stream>>>(Wv, wvb, N * K);
    cvt_f32_bf16<<<1024, 256, 0, stream>>>(Wo, wob, N * K);
    pack_mask<<<LSEQ, 256, 0, stream>>>(mask, mb);

    const int gblocks = (M / 128) * (N / 128);  // 512
    gemm_bt<0><<<gblocks, 256, 0, stream>>>(xb, wqb, bq, qb, M, N, K, cs);
    gemm_bt<0><<<gblocks, 256, 0, stream>>>(xb, wkb, bk, kb, M, N, K, 1.0f);
    gemm_bt<0><<<gblocks, 256, 0, stream>>>(xb, wvb, bv, vb, M, N, K, 1.0f);

    attn_fwd<<<(LSEQ / 64) * 64, 256, 0, stream>>>(qb, kb, vb, mb, ab);

    gemm_bt<1><<<gblocks, 256, 0, stream>>>(ab, wob, bo, d_out, M, N, K, 1.0f);
}

// Round 6
// 297.030 us; speedup vs baseline: 1.5871x; 1.1892x over previous
//
#include <hip/hip_runtime.h>
#include <stdint.h>

#define LSEQ 2048
#define DMODEL 1024
#define NHEADS 16
#define HDIM 64
#define NBATCH 4

typedef __attribute__((ext_vector_type(8))) __bf16 bf16x8;
typedef __attribute__((ext_vector_type(4))) __bf16 bf16x4;
typedef __attribute__((ext_vector_type(4))) float f32x4;
typedef __attribute__((ext_vector_type(4))) uint32_t u32x4;
typedef __attribute__((ext_vector_type(8))) uint16_t u16x8;

__device__ inline float fexp2(float x) {
#if __has_builtin(__builtin_amdgcn_exp2f)
    return __builtin_amdgcn_exp2f(x);
#else
    float r; asm("v_exp_f32 %0, %1" : "=v"(r) : "v"(x)); return r;
#endif
}

// ---------------------------------------------------------------------------
// async global->LDS 16B copy (LDS dest = wave-uniform base + lane*16)
// ---------------------------------------------------------------------------
__device__ inline void gload_lds16(const void* g, const void* l) {
    auto gp = reinterpret_cast<const uint32_t __attribute__((address_space(1)))*>(
        reinterpret_cast<uintptr_t>(g));
    auto lp = reinterpret_cast<uint32_t __attribute__((address_space(3)))*>(
        (uint32_t)(uintptr_t)(l));
    __builtin_amdgcn_global_load_lds(gp, lp, 16, 0, 0);
}

// ---------------------------------------------------------------------------
// fp32 -> bf16 convert (vectorized)
// ---------------------------------------------------------------------------
__global__ void cvt_f32_bf16(const float* __restrict__ src, __bf16* __restrict__ dst, int n) {
    int idx = blockIdx.x * blockDim.x + threadIdx.x;
    int stride = gridDim.x * blockDim.x;
    for (int i = idx * 4; i < n; i += stride * 4) {
        float4 f = *(const float4*)(src + i);
        bf16x4 v;
        v[0] = (__bf16)f.x; v[1] = (__bf16)f.y; v[2] = (__bf16)f.z; v[3] = (__bf16)f.w;
        *(bf16x4*)(dst + i) = v;
    }
}

// ---------------------------------------------------------------------------
// mask bit-pack: int32 [2048][2048] -> uint64 [2048][32] via __ballot
// ---------------------------------------------------------------------------
__global__ void pack_mask(const int* __restrict__ mask, unsigned long long* __restrict__ mbits) {
    const int row = blockIdx.x;
    const int w = threadIdx.x >> 6, lane = threadIdx.x & 63;
    const int* mrow = mask + (size_t)row * LSEQ;
#pragma unroll
    for (int it = 0; it < 8; it++) {
        const int c = it * 256 + w * 64 + lane;
        const unsigned long long b = __ballot(mrow[c] != 0);
        if (lane == 0) mbits[(size_t)row * 32 + it * 4 + w] = b;
    }
}

// ---------------------------------------------------------------------------
// GEMM: C[m][n] = sum_k A[m][k]*Bw[n][k] + bias[n]   (both row-major, NT)
// 128x128 tile, BK=32, 4 waves (2x2), mfma_f32_16x16x32_bf16, m97 structure.
// MODE 0: bf16*(scale) into per-head layout [b][h][l][d];  MODE 1: fp32 row-major
// ---------------------------------------------------------------------------
template <int MODE>
__global__ __launch_bounds__(256) void gemm_bt(const __bf16* __restrict__ A,
                                               const __bf16* __restrict__ Bw,
                                               const float* __restrict__ bias,
                                               void* __restrict__ Cout,
                                               int M, int N, int K, float scale) {
    __shared__ __bf16 As[128 * 32];
    __shared__ __bf16 Bs[128 * 32];

    const int nbn = N >> 7;
    const int bm = (blockIdx.x / nbn) << 7;
    const int bn = (blockIdx.x % nbn) << 7;
    const int tid = threadIdx.x;
    const int w = tid >> 6, lane = tid & 63;
    const int l15 = lane & 15, l4 = lane >> 4;
    const int wm = (w >> 1) * 64, wn = (w & 1) * 64;

    f32x4 acc[4][4];
    for (int i = 0; i < 4; i++)
        for (int j = 0; j < 4; j++)
            acc[i][j] = (f32x4){0.f, 0.f, 0.f, 0.f};

    const int fa0 = (w * 2 + 0) * 64 + lane;
    const int fa1 = (w * 2 + 1) * 64 + lane;
    const __bf16* gA0 = A + (size_t)(bm + (fa0 >> 2)) * K + (fa0 & 3) * 8;
    const __bf16* gA1 = A + (size_t)(bm + (fa1 >> 2)) * K + (fa1 & 3) * 8;
    const __bf16* gB0 = Bw + (size_t)(bn + (fa0 >> 2)) * K + (fa0 & 3) * 8;
    const __bf16* gB1 = Bw + (size_t)(bn + (fa1 >> 2)) * K + (fa1 & 3) * 8;
    const __bf16* lA0 = &As[(w * 2 + 0) * 512];
    const __bf16* lA1 = &As[(w * 2 + 1) * 512];
    const __bf16* lB0 = &Bs[(w * 2 + 0) * 512];
    const __bf16* lB1 = &Bs[(w * 2 + 1) * 512];

    for (int kt = 0; kt < K; kt += 32) {
        __syncthreads();
        gload_lds16(gA0 + kt, lA0);
        gload_lds16(gA1 + kt, lA1);
        gload_lds16(gB0 + kt, lB0);
        gload_lds16(gB1 + kt, lB1);
        __syncthreads();

        bf16x8 af[4], bw[4];
        for (int i = 0; i < 4; i++)
            af[i] = *(const bf16x8*)&As[(wm + i * 16 + l15) * 32 + l4 * 8];
        for (int j = 0; j < 4; j++)
            bw[j] = *(const bf16x8*)&Bs[(wn + j * 16 + l15) * 32 + l4 * 8];
        for (int i = 0; i < 4; i++)
            for (int j = 0; j < 4; j++)
                acc[i][j] = __builtin_amdgcn_mfma_f32_16x16x32_bf16(af[i], bw[j], acc[i][j], 0, 0, 0);
    }

    for (int i = 0; i < 4; i++) {
        const int row0 = bm + wm + i * 16 + l4 * 4;
        for (int j = 0; j < 4; j++) {
            const int col = bn + wn + j * 16 + l15;
            const float bv = bias[col];
            if (MODE == 0) {
                __bf16* dst = (__bf16*)Cout;
                const int h = col >> 6, d = col & 63;
                for (int jj = 0; jj < 4; jj++) {
                    const int r = row0 + jj;
                    const int b = r >> 11, l = r & (LSEQ - 1);
                    dst[(((size_t)(b * NHEADS + h) * LSEQ + l) << 6) + d] =
                        (__bf16)((acc[i][j][jj] + bv) * scale);
                }
            } else {
                float* dst = (float*)Cout;
                for (int jj = 0; jj < 4; jj++) {
                    const int r = row0 + jj;
                    dst[(size_t)r * N + col] = acc[i][j][jj] + bv;
                }
            }
        }
    }
}

// ---------------------------------------------------------------------------
// Flash attention, SWAPPED QK^T (T12-style): Z = mfma(K_frag, Q_frag) puts
// S^T[k = f*16 + l4*4 + jj][q = l15] in lane (l4,l15) -> softmax reduction is
// lane-local (15 fmax + 2 shfl); m/l/alpha are lane-scalars for q = l15.
// P store: 4x ds_write_b64 into per-wave Ps2[16 q-rows][144B] with byte-XOR
// swizzle ^((l15&3)<<5); PV A-fragment = 2x b128 reads with the same XOR.
// K: linear LDS via gload_lds + 16B-chunk XOR (unchanged addresses; A/B
// fragment lane-maps are identical for 16x16x32). V: reg-staged k-pair
// transposed LDS (unchanged). Mask: 1 uint2 load/lane/tile.
// ---------------------------------------------------------------------------
__global__ __launch_bounds__(256) void attn_fwd(const __bf16* __restrict__ Q,
                                                const __bf16* __restrict__ Kk,
                                                const __bf16* __restrict__ V,
                                                const unsigned long long* __restrict__ mbits,
                                                __bf16* __restrict__ Oout) {
    const int bh = blockIdx.x & 63;
    const int qt = blockIdx.x >> 6;
    const int tid = threadIdx.x;
    const int w = tid >> 6, lane = tid & 63;
    const int l15 = lane & 15, l4 = lane >> 4, l7 = l15 & 7;

    __shared__ __bf16 Ks[64 * 64];       // row-major, 16B-chunk XOR swizzle
    __shared__ uint32_t Vt32[64][32];    // [d][kpair], block-XOR swizzled
    __shared__ __bf16 Ps2[4][16][72];    // per-wave P^T->P tile; 144B rows

    const int q0 = qt * 64 + w * 16;
    const __bf16* qbase = Q + ((size_t)bh * LSEQ + q0 + l15) * HDIM + l4 * 8;
    const bf16x8 aq0 = *(const bf16x8*)(qbase);
    const bf16x8 aq1 = *(const bf16x8*)(qbase + 32);

    f32x4 o[4];
    for (int f = 0; f < 4; f++) o[f] = (f32x4){0.f, 0.f, 0.f, 0.f};
    float m_run = -1.0e30f, l_run = 0.f;

    // ---- K staging (16B chunks; 512 chunks per 8KB tile) ----
    const int ck0 = w * 64 + lane;
    const int ck1 = ck0 + 256;
    const int koff0 = ((ck0 >> 3) << 7) + ((((ck0 & 7) ^ ((ck0 >> 3) & 7))) << 4);
    const int koff1 = ((ck1 >> 3) << 7) + ((((ck1 & 7) ^ ((ck1 >> 3) & 7))) << 4);
    const char* kp0 = (const char*)(Kk + (size_t)bh * LSEQ * HDIM) + koff0;
    const char* kp1 = (const char*)(Kk + (size_t)bh * LSEQ * HDIM) + koff1;
    __bf16* ldsK0 = &Ks[w * 512];
    __bf16* ldsK1 = &Ks[w * 512 + 2048];

    // K fragment read (byte) addrs: row*128 + 16*((ks*4+l4)^l7), row = f*16+l15
    const int kread0 = l15 * 128 + ((l4 ^ l7) << 4);
    const int kread1 = l15 * 128 + (((4 + l4) ^ l7) << 4);
    // V fragment read (word) addrs: row*32 + 4*((ks*4+l4)^l7), row = f*16+l15
    const int vread0 = l15 * 32 + ((l4 ^ l7) << 2);
    const int vread1 = l15 * 32 + (((4 + l4) ^ l7) << 2);
    const uint32_t* vbase = &Vt32[0][0];

    // V staging: thread -> k-pair kp (rows 2kp,2kp+1), d-chunk d0..d0+7
    const int kpi = tid & 31;
    const int d0 = (tid >> 5) * 8;
    const __bf16* vp0 = V + (size_t)bh * LSEQ * HDIM + (size_t)(2 * kpi) * HDIM + d0;
    const __bf16* vp1 = vp0 + HDIM;

    // Ps2 addressing: per-wave q-row l15, byte XOR swizzle
    char* ps2row = (char*)&Ps2[w][l15][0];
    const int xr = (l15 & 3) << 5;
    const int pw0 = (0 * 32 + l4 * 8) ^ xr;   // write offs (per f: +32 logical)
    const int pw1 = (1 * 32 + l4 * 8) ^ xr;
    const int pw2 = (2 * 32 + l4 * 8) ^ xr;
    const int pw3 = (3 * 32 + l4 * 8) ^ xr;
    const int pr0 = (0 * 64 + l4 * 16) ^ xr;  // read offs (ks = 0,1)
    const int pr1 = (1 * 64 + l4 * 16) ^ xr;

    // mask: lane's q-row word stream
    const uint2* mptr = (const uint2*)(mbits + (size_t)(q0 + l15) * 32);
    const int sh4 = l4 * 4;

    for (int kt = 0; kt < LSEQ; kt += 64) {
        // V tile -> regs (global; issued before the barrier to hide latency)
        const u16x8 vr0 = *(const u16x8*)(vp0);
        const u16x8 vr1 = *(const u16x8*)(vp1);
        vp0 += 64 * HDIM; vp1 += 64 * HDIM;

        __syncthreads();   // all waves done reading prev tile's Ks/Vt32

        gload_lds16(kp0, ldsK0);
        gload_lds16(kp1, ldsK1);
        kp0 += 64 * HDIM * 2; kp1 += 64 * HDIM * 2;

        // mask word for q=l15 (one 8B load; pre-shift so bit (f*16+jj) tests)
        const uint2 mw = mptr[kt >> 6];
        const uint32_t mlo = mw.x >> sh4;
        const uint32_t mhi = mw.y >> sh4;

        // V regs -> LDS transposed-pair layout via v_perm
        {
            const uint32_t* a = (const uint32_t*)&vr0;
            const uint32_t* b = (const uint32_t*)&vr1;
#pragma unroll
            for (int jp = 0; jp < 4; jp++) {
                const uint32_t w0 = __builtin_amdgcn_perm(b[jp], a[jp], 0x05040100u);
                const uint32_t w1 = __builtin_amdgcn_perm(b[jp], a[jp], 0x07060302u);
                const int j0 = jp * 2, j1 = jp * 2 + 1;
                Vt32[d0 + j0][(kpi & 3) | (((kpi >> 2) ^ j0) << 2)] = w0;
                Vt32[d0 + j1][(kpi & 3) | (((kpi >> 2) ^ j1) << 2)] = w1;
            }
        }

        __syncthreads();

        // ---- S^T = K Q^T : lane holds S[k=f*16+l4*4+jj][q=l15] ----
        f32x4 sf[4];
        __builtin_amdgcn_s_setprio(1);
#pragma unroll
        for (int f = 0; f < 4; f++) {
            const bf16x8 bk0 = *(const bf16x8*)((const char*)Ks + f * 2048 + kread0);
            const bf16x8 bk1 = *(const bf16x8*)((const char*)Ks + f * 2048 + kread1);
            f32x4 z = (f32x4){0.f, 0.f, 0.f, 0.f};
            z = __builtin_amdgcn_mfma_f32_16x16x32_bf16(bk0, aq0, z, 0, 0, 0);
            z = __builtin_amdgcn_mfma_f32_16x16x32_bf16(bk1, aq1, z, 0, 0, 0);
            sf[f] = z;
        }
        __builtin_amdgcn_s_setprio(0);

        // ---- lane-local max over 16 values + 2-shfl merge across l4 ----
        float vmx;
        {
            float a0 = fmaxf(fmaxf(sf[0][0], sf[0][1]), fmaxf(sf[0][2], sf[0][3]));
            float a1 = fmaxf(fmaxf(sf[1][0], sf[1][1]), fmaxf(sf[1][2], sf[1][3]));
            float a2 = fmaxf(fmaxf(sf[2][0], sf[2][1]), fmaxf(sf[2][2], sf[2][3]));
            float a3 = fmaxf(fmaxf(sf[3][0], sf[3][1]), fmaxf(sf[3][2], sf[3][3]));
            vmx = fmaxf(fmaxf(a0, a1), fmaxf(a2, a3));
            vmx = fmaxf(vmx, __shfl_xor(vmx, 16));
            vmx = fmaxf(vmx, __shfl_xor(vmx, 32));
        }

        // ---- defer-max: rescale only when max grew by > 8 octaves ----
        if (__any(vmx > m_run + 8.f)) {
            const float mnew = fmaxf(m_run, vmx);
            const float alpha = fexp2(m_run - mnew);
            m_run = mnew;
            l_run *= alpha;
            float aO[4];
#pragma unroll
            for (int jj = 0; jj < 4; jj++) aO[jj] = __shfl(alpha, l4 * 4 + jj);
#pragma unroll
            for (int f = 0; f < 4; f++)
#pragma unroll
                for (int jj = 0; jj < 4; jj++) o[f][jj] *= aO[jj];
        }

        // ---- P = exp2(S - m), mask-zero, per-lane l partial, pack, store ----
        float ps = 0.f;
#pragma unroll
        for (int f = 0; f < 4; f++) {
            const uint32_t mword = (f < 2) ? mlo : mhi;
            const int mb = (f & 1) * 16;
            bf16x4 pk;
#pragma unroll
            for (int jj = 0; jj < 4; jj++) {
                float e = fexp2(sf[f][jj] - m_run);
                e = ((mword >> (mb + jj)) & 1u) ? e : 0.f;
                ps += e;
                pk[jj] = (__bf16)e;
            }
            const int off = (f == 0) ? pw0 : (f == 1) ? pw1 : (f == 2) ? pw2 : pw3;
            *(bf16x4*)(ps2row + off) = pk;
        }
        l_run += ps;

        __builtin_amdgcn_sched_barrier(0);
        const bf16x8 pa0 = *(const bf16x8*)(ps2row + pr0);
        const bf16x8 pa1 = *(const bf16x8*)(ps2row + pr1);

        // ---- O += P V ----
        __builtin_amdgcn_s_setprio(1);
#pragma unroll
        for (int f = 0; f < 4; f++) {
            const bf16x8 bv0 = __builtin_bit_cast(bf16x8, *(const u32x4*)(vbase + f * 512 + vread0));
            const bf16x8 bv1 = __builtin_bit_cast(bf16x8, *(const u32x4*)(vbase + f * 512 + vread1));
            o[f] = __builtin_amdgcn_mfma_f32_16x16x32_bf16(pa0, bv0, o[f], 0, 0, 0);
            o[f] = __builtin_amdgcn_mfma_f32_16x16x32_bf16(pa1, bv1, o[f], 0, 0, 0);
        }
        __builtin_amdgcn_s_setprio(0);
    }

    // epilogue: merge l across l4-groups, redistribute to O-rows, write bf16
    const int b = bh >> 4, h = bh & 15;
    float s = l_run;
    s += __shfl_xor(s, 16);
    s += __shfl_xor(s, 32);
    const float inv = 1.0f / fmaxf(s, 1e-30f);
#pragma unroll
    for (int jj = 0; jj < 4; jj++) {
        const float invj = __shfl(inv, l4 * 4 + jj);
        const int l = q0 + l4 * 4 + jj;
#pragma unroll
        for (int f = 0; f < 4; f++)
            Oout[((size_t)b * LSEQ + l) * DMODEL + h * HDIM + f * 16 + l15] =
                (__bf16)(o[f][jj] * invj);
    }
}

// ---------------------------------------------------------------------------
extern "C" void kernel_launch(void* const* d_in, const int* in_sizes, int n_in,
                              void* d_out, int out_size, void* d_ws, size_t ws_size,
                              hipStream_t stream) {
    const float* x  = (const float*)d_in[0];
    const int* mask = (const int*)d_in[1];
    const float* Wq = (const float*)d_in[2];
    const float* bq = (const float*)d_in[3];
    const float* Wk = (const float*)d_in[4];
    const float* bk = (const float*)d_in[5];
    const float* Wv = (const float*)d_in[6];
    const float* bv = (const float*)d_in[7];
    const float* Wo = (const float*)d_in[8];
    const float* bo = (const float*)d_in[9];

    char* ws = (char*)d_ws;
    __bf16* xb  = (__bf16*)(ws);                    // 16 MiB  [8192][1024]
    __bf16* wqb = (__bf16*)(ws + (16u << 20));      // 2 MiB
    __bf16* wkb = (__bf16*)(ws + (18u << 20));
    __bf16* wvb = (__bf16*)(ws + (20u << 20));
    __bf16* wob = (__bf16*)(ws + (22u << 20));
    __bf16* qb  = (__bf16*)(ws + (24u << 20));      // 16 MiB  [b][h][l][64]
    __bf16* kb  = (__bf16*)(ws + (40u << 20));
    __bf16* vb  = (__bf16*)(ws + (56u << 20));
    __bf16* ab  = (__bf16*)(ws + (72u << 20));      // 16 MiB  [b][l][1024]
    unsigned long long* mb = (unsigned long long*)(ws + (88u << 20));  // 512 KiB

    const int M = NBATCH * LSEQ;   // 8192
    const int N = DMODEL;          // 1024
    const int K = DMODEL;          // 1024
    const float cs = 0.18033688011112f;   // 0.125 * log2(e), folded into Q

    cvt_f32_bf16<<<2048, 256, 0, stream>>>(x, xb, M * K);
    cvt_f32_bf16<<<1024, 256, 0, stream>>>(Wq, wqb, N * K);
    cvt_f32_bf16<<<1024, 256, 0, stream>>>(Wk, wkb, N * K);
    cvt_f32_bf16<<<1024, 256, 0, stream>>>(Wv, wvb, N * K);
    cvt_f32_bf16<<<1024, 256, 0, stream>>>(Wo, wob, N * K);
    pack_mask<<<LSEQ, 256, 0, stream>>>(mask, mb);

    const int gblocks = (M / 128) * (N / 128);  // 512
    gemm_bt<0><<<gblocks, 256, 0, stream>>>(xb, wqb, bq, qb, M, N, K, cs);
    gemm_bt<0><<<gblocks, 256, 0, stream>>>(xb, wkb, bk, kb, M, N, K, 1.0f);
    gemm_bt<0><<<gblocks, 256, 0, stream>>>(xb, wvb, bv, vb, M, N, K, 1.0f);

    attn_fwd<<<(LSEQ / 64) * 64, 256, 0, stream>>>(qb, kb, vb, mb, ab);

    gemm_bt<1><<<gblocks, 256, 0, stream>>>(ab, wob, bo, d_out, M, N, K, 1.0f);
}

// Round 7
// 276.874 us; speedup vs baseline: 1.7026x; 1.0728x over previous
//
#include <hip/hip_runtime.h>
#include <stdint.h>

#define LSEQ 2048
#define DMODEL 1024
#define NHEADS 16
#define HDIM 64
#define NBATCH 4

typedef __attribute__((ext_vector_type(8))) __bf16 bf16x8;
typedef __attribute__((ext_vector_type(4))) __bf16 bf16x4;
typedef __attribute__((ext_vector_type(4))) float f32x4;
typedef __attribute__((ext_vector_type(4))) uint32_t u32x4;
typedef __attribute__((ext_vector_type(8))) uint16_t u16x8;

__device__ inline float fexp2(float x) {
#if __has_builtin(__builtin_amdgcn_exp2f)
    return __builtin_amdgcn_exp2f(x);
#else
    float r; asm("v_exp_f32 %0, %1" : "=v"(r) : "v"(x)); return r;
#endif
}

// ---------------------------------------------------------------------------
// async global->LDS 16B copy (LDS dest = wave-uniform base + lane*16)
// ---------------------------------------------------------------------------
__device__ inline void gload_lds16(const void* g, const void* l) {
    auto gp = reinterpret_cast<const uint32_t __attribute__((address_space(1)))*>(
        reinterpret_cast<uintptr_t>(g));
    auto lp = reinterpret_cast<uint32_t __attribute__((address_space(3)))*>(
        (uint32_t)(uintptr_t)(l));
    __builtin_amdgcn_global_load_lds(gp, lp, 16, 0, 0);
}

// ---------------------------------------------------------------------------
// fp32 -> bf16 convert (vectorized); x activations
// ---------------------------------------------------------------------------
__global__ void cvt_f32_bf16(const float* __restrict__ src, __bf16* __restrict__ dst, int n) {
    int idx = blockIdx.x * blockDim.x + threadIdx.x;
    int stride = gridDim.x * blockDim.x;
    for (int i = idx * 4; i < n; i += stride * 4) {
        float4 f = *(const float4*)(src + i);
        bf16x4 v;
        v[0] = (__bf16)f.x; v[1] = (__bf16)f.y; v[2] = (__bf16)f.z; v[3] = (__bf16)f.w;
        *(bf16x4*)(dst + i) = v;
    }
}

// all 4 weight matrices (1M fp32 each) -> one contiguous bf16 region
__global__ void cvt_w4(const float* __restrict__ a, const float* __restrict__ b,
                       const float* __restrict__ c, const float* __restrict__ d,
                       __bf16* __restrict__ dst) {
    const int t = blockIdx.x * blockDim.x + threadIdx.x;   // 0..1048575
    const int i4 = t * 4;
    const int m = i4 >> 20;
    const int off = i4 & ((1 << 20) - 1);
    const float* src = (m == 0) ? a : (m == 1) ? b : (m == 2) ? c : d;
    float4 f = *(const float4*)(src + off);
    bf16x4 v;
    v[0] = (__bf16)f.x; v[1] = (__bf16)f.y; v[2] = (__bf16)f.z; v[3] = (__bf16)f.w;
    *(bf16x4*)(dst + i4) = v;
}

__global__ void pack_bias(const float* __restrict__ bq, const float* __restrict__ bk,
                          const float* __restrict__ bv, float* __restrict__ dst) {
    const int i = blockIdx.x * 256 + threadIdx.x;   // grid 12 x 256 = 3072
    dst[i] = (i < 1024) ? bq[i] : (i < 2048) ? bk[i - 1024] : bv[i - 2048];
}

// ---------------------------------------------------------------------------
// mask bit-pack: int32 [2048][2048] -> uint64 [2048][32] via __ballot
// ---------------------------------------------------------------------------
__global__ void pack_mask(const int* __restrict__ mask, unsigned long long* __restrict__ mbits) {
    const int row = blockIdx.x;
    const int w = threadIdx.x >> 6, lane = threadIdx.x & 63;
    const int* mrow = mask + (size_t)row * LSEQ;
#pragma unroll
    for (int it = 0; it < 8; it++) {
        const int c = it * 256 + w * 64 + lane;
        const unsigned long long b = __ballot(mrow[c] != 0);
        if (lane == 0) mbits[(size_t)row * 32 + it * 4 + w] = b;
    }
}

// ---------------------------------------------------------------------------
// GEMM: C[m][n] = sum_k A[m][k]*Bw[n][k] + bias[n]   (both row-major, NT)
// 128x128 tile, BK=32, 4 waves (2x2), mfma_f32_16x16x32_bf16, m97 structure.
// MODE 0: merged-QKV epilogue (N=3072): which=col>>10 selects q/k/v dest
//         (contiguous, 8M elements apart); bf16 per-head layout [b][h][l][d];
//         scale applied to q only.
// MODE 1: fp32 row-major
// ---------------------------------------------------------------------------
template <int MODE>
__global__ __launch_bounds__(256) void gemm_bt(const __bf16* __restrict__ A,
                                               const __bf16* __restrict__ Bw,
                                               const float* __restrict__ bias,
                                               void* __restrict__ Cout,
                                               int M, int N, int K, float scale) {
    __shared__ __bf16 As[128 * 32];
    __shared__ __bf16 Bs[128 * 32];

    const int nbn = N >> 7;
    const int bm = (blockIdx.x / nbn) << 7;
    const int bn = (blockIdx.x % nbn) << 7;
    const int tid = threadIdx.x;
    const int w = tid >> 6, lane = tid & 63;
    const int l15 = lane & 15, l4 = lane >> 4;
    const int wm = (w >> 1) * 64, wn = (w & 1) * 64;

    f32x4 acc[4][4];
    for (int i = 0; i < 4; i++)
        for (int j = 0; j < 4; j++)
            acc[i][j] = (f32x4){0.f, 0.f, 0.f, 0.f};

    const int fa0 = (w * 2 + 0) * 64 + lane;
    const int fa1 = (w * 2 + 1) * 64 + lane;
    const __bf16* gA0 = A + (size_t)(bm + (fa0 >> 2)) * K + (fa0 & 3) * 8;
    const __bf16* gA1 = A + (size_t)(bm + (fa1 >> 2)) * K + (fa1 & 3) * 8;
    const __bf16* gB0 = Bw + (size_t)(bn + (fa0 >> 2)) * K + (fa0 & 3) * 8;
    const __bf16* gB1 = Bw + (size_t)(bn + (fa1 >> 2)) * K + (fa1 & 3) * 8;
    const __bf16* lA0 = &As[(w * 2 + 0) * 512];
    const __bf16* lA1 = &As[(w * 2 + 1) * 512];
    const __bf16* lB0 = &Bs[(w * 2 + 0) * 512];
    const __bf16* lB1 = &Bs[(w * 2 + 1) * 512];

    for (int kt = 0; kt < K; kt += 32) {
        __syncthreads();
        gload_lds16(gA0 + kt, lA0);
        gload_lds16(gA1 + kt, lA1);
        gload_lds16(gB0 + kt, lB0);
        gload_lds16(gB1 + kt, lB1);
        __syncthreads();

        bf16x8 af[4], bw[4];
        for (int i = 0; i < 4; i++)
            af[i] = *(const bf16x8*)&As[(wm + i * 16 + l15) * 32 + l4 * 8];
        for (int j = 0; j < 4; j++)
            bw[j] = *(const bf16x8*)&Bs[(wn + j * 16 + l15) * 32 + l4 * 8];
        for (int i = 0; i < 4; i++)
            for (int j = 0; j < 4; j++)
                acc[i][j] = __builtin_amdgcn_mfma_f32_16x16x32_bf16(af[i], bw[j], acc[i][j], 0, 0, 0);
    }

    for (int i = 0; i < 4; i++) {
        const int row0 = bm + wm + i * 16 + l4 * 4;
        for (int j = 0; j < 4; j++) {
            const int col = bn + wn + j * 16 + l15;
            const float bv = bias[col];
            if (MODE == 0) {
                __bf16* dst = (__bf16*)Cout;
                const int which = col >> 10;
                const int cr = col & 1023;
                const int h = cr >> 6, d = cr & 63;
                const float scl = (which == 0) ? scale : 1.0f;
                for (int jj = 0; jj < 4; jj++) {
                    const int r = row0 + jj;
                    const int b = r >> 11, l = r & (LSEQ - 1);
                    dst[((size_t)which << 23) +
                        (((size_t)(b * NHEADS + h) * LSEQ + l) << 6) + d] =
                        (__bf16)((acc[i][j][jj] + bv) * scl);
                }
            } else {
                float* dst = (float*)Cout;
                for (int jj = 0; jj < 4; jj++) {
                    const int r = row0 + jj;
                    dst[(size_t)r * N + col] = acc[i][j][jj] + bv;
                }
            }
        }
    }
}

// ---------------------------------------------------------------------------
// V store helper: k-pair transposed layout with 4-word-block XOR swizzle
// ---------------------------------------------------------------------------
__device__ inline void storeV(uint32_t (*vt)[32], int kpi, int d0,
                              const u16x8& r0, const u16x8& r1) {
    const uint32_t* a = (const uint32_t*)&r0;
    const uint32_t* b = (const uint32_t*)&r1;
#pragma unroll
    for (int jp = 0; jp < 4; jp++) {
        const uint32_t w0 = __builtin_amdgcn_perm(b[jp], a[jp], 0x05040100u);
        const uint32_t w1 = __builtin_amdgcn_perm(b[jp], a[jp], 0x07060302u);
        const int j0 = jp * 2, j1 = jp * 2 + 1;
        vt[d0 + j0][(kpi & 3) | (((kpi >> 2) ^ j0) << 2)] = w0;
        vt[d0 + j1][(kpi & 3) | (((kpi >> 2) ^ j1) << 2)] = w1;
    }
}

// ---------------------------------------------------------------------------
// Flash attention, swapped QK^T, single-barrier double-buffered staging:
// per tile: issue V-glb(t+1)+K-gload(t+1)->buf^1, QK/softmax on buf,
// V-perm+write(t+1)->buf^1, PV on buf, ONE __syncthreads. Issue-to-drain
// distance ~= one compute phase (vs zero in the 2-barrier version).
// ---------------------------------------------------------------------------
__global__ __launch_bounds__(256) void attn_fwd(const __bf16* __restrict__ Q,
                                                const __bf16* __restrict__ Kk,
                                                const __bf16* __restrict__ V,
                                                const unsigned long long* __restrict__ mbits,
                                                __bf16* __restrict__ Oout) {
    const int bh = blockIdx.x & 63;
    const int qt = blockIdx.x >> 6;
    const int tid = threadIdx.x;
    const int w = tid >> 6, lane = tid & 63;
    const int l15 = lane & 15, l4 = lane >> 4, l7 = l15 & 7;

    __shared__ __bf16 Ks[2][64 * 64];     // dbuf; row-major, 16B-chunk XOR swizzle
    __shared__ uint32_t Vt32[2][64][32];  // dbuf; [d][kpair], block-XOR swizzled
    __shared__ __bf16 Ps2[4][16][72];     // per-wave P tile; 144B rows

    const int q0 = qt * 64 + w * 16;
    const __bf16* qbase = Q + ((size_t)bh * LSEQ + q0 + l15) * HDIM + l4 * 8;
    const bf16x8 aq0 = *(const bf16x8*)(qbase);
    const bf16x8 aq1 = *(const bf16x8*)(qbase + 32);

    f32x4 o[4];
    for (int f = 0; f < 4; f++) o[f] = (f32x4){0.f, 0.f, 0.f, 0.f};
    float m_run = -1.0e30f, l_run = 0.f;

    // ---- K staging (16B chunks; 512 chunks per 8KB tile) ----
    const int ck0 = w * 64 + lane;
    const int ck1 = ck0 + 256;
    const int koff0 = ((ck0 >> 3) << 7) + ((((ck0 & 7) ^ ((ck0 >> 3) & 7))) << 4);
    const int koff1 = ((ck1 >> 3) << 7) + ((((ck1 & 7) ^ ((ck1 >> 3) & 7))) << 4);
    const char* kp0 = (const char*)(Kk + (size_t)bh * LSEQ * HDIM) + koff0;
    const char* kp1 = (const char*)(Kk + (size_t)bh * LSEQ * HDIM) + koff1;
    const int kdst0 = w * 512;          // element offset within Ks[x]
    const int kdst1 = w * 512 + 2048;

    // K fragment read (byte) addrs: row*128 + 16*((ks*4+l4)^l7), row = f*16+l15
    const int kread0 = l15 * 128 + ((l4 ^ l7) << 4);
    const int kread1 = l15 * 128 + (((4 + l4) ^ l7) << 4);
    // V fragment read (word) addrs: row*32 + 4*((ks*4+l4)^l7), row = f*16+l15
    const int vread0 = l15 * 32 + ((l4 ^ l7) << 2);
    const int vread1 = l15 * 32 + (((4 + l4) ^ l7) << 2);

    // V staging: thread -> k-pair kpi (rows 2kpi,2kpi+1), d-chunk d0..d0+7
    const int kpi = tid & 31;
    const int d0 = (tid >> 5) * 8;
    const __bf16* vp0 = V + (size_t)bh * LSEQ * HDIM + (size_t)(2 * kpi) * HDIM + d0;
    const __bf16* vp1 = vp0 + HDIM;

    // Ps2 addressing: per-wave q-row l15, byte XOR swizzle
    char* ps2row = (char*)&Ps2[w][l15][0];
    const int xr = (l15 & 3) << 5;
    const int pw0 = (0 * 32 + l4 * 8) ^ xr;
    const int pw1 = (1 * 32 + l4 * 8) ^ xr;
    const int pw2 = (2 * 32 + l4 * 8) ^ xr;
    const int pw3 = (3 * 32 + l4 * 8) ^ xr;
    const int pr0 = (0 * 64 + l4 * 16) ^ xr;
    const int pr1 = (1 * 64 + l4 * 16) ^ xr;

    // mask: lane's q-row word stream (one uint2 per 64-col tile)
    const uint2* mptr = (const uint2*)(mbits + (size_t)(q0 + l15) * 32);
    const int sh4 = l4 * 4;

    // ---- prologue: stage tile 0 into buffer 0 ----
    {
        const u16x8 v0 = *(const u16x8*)(vp0);
        const u16x8 v1 = *(const u16x8*)(vp1);
        vp0 += 64 * HDIM; vp1 += 64 * HDIM;
        gload_lds16(kp0, &Ks[0][kdst0]);
        gload_lds16(kp1, &Ks[0][kdst1]);
        kp0 += 8192; kp1 += 8192;
        storeV(Vt32[0], kpi, d0, v0, v1);
    }
    __syncthreads();

    int cur = 0;
    const int NT = LSEQ / 64;   // 32
    for (int t = 0; t < NT; t++) {
        const int nx = cur ^ 1;
        u16x8 nv0, nv1;
        if (t < NT - 1) {
            nv0 = *(const u16x8*)(vp0);
            nv1 = *(const u16x8*)(vp1);
            vp0 += 64 * HDIM; vp1 += 64 * HDIM;
            gload_lds16(kp0, &Ks[nx][kdst0]);
            gload_lds16(kp1, &Ks[nx][kdst1]);
            kp0 += 8192; kp1 += 8192;
        }

        const uint2 mw = mptr[t];
        const uint32_t mlo = mw.x >> sh4;
        const uint32_t mhi = mw.y >> sh4;

        // ---- S^T = K Q^T : lane holds S[k=f*16+l4*4+jj][q=l15] ----
        const char* ksb = (const char*)&Ks[cur][0];
        f32x4 sf[4];
        __builtin_amdgcn_s_setprio(1);
#pragma unroll
        for (int f = 0; f < 4; f++) {
            const bf16x8 bk0 = *(const bf16x8*)(ksb + f * 2048 + kread0);
            const bf16x8 bk1 = *(const bf16x8*)(ksb + f * 2048 + kread1);
            f32x4 z = (f32x4){0.f, 0.f, 0.f, 0.f};
            z = __builtin_amdgcn_mfma_f32_16x16x32_bf16(bk0, aq0, z, 0, 0, 0);
            z = __builtin_amdgcn_mfma_f32_16x16x32_bf16(bk1, aq1, z, 0, 0, 0);
            sf[f] = z;
        }
        __builtin_amdgcn_s_setprio(0);

        // ---- lane-local max + 2-shfl merge ----
        float vmx;
        {
            float a0 = fmaxf(fmaxf(sf[0][0], sf[0][1]), fmaxf(sf[0][2], sf[0][3]));
            float a1 = fmaxf(fmaxf(sf[1][0], sf[1][1]), fmaxf(sf[1][2], sf[1][3]));
            float a2 = fmaxf(fmaxf(sf[2][0], sf[2][1]), fmaxf(sf[2][2], sf[2][3]));
            float a3 = fmaxf(fmaxf(sf[3][0], sf[3][1]), fmaxf(sf[3][2], sf[3][3]));
            vmx = fmaxf(fmaxf(a0, a1), fmaxf(a2, a3));
            vmx = fmaxf(vmx, __shfl_xor(vmx, 16));
            vmx = fmaxf(vmx, __shfl_xor(vmx, 32));
        }

        // ---- defer-max ----
        if (__any(vmx > m_run + 8.f)) {
            const float mnew = fmaxf(m_run, vmx);
            const float alpha = fexp2(m_run - mnew);
            m_run = mnew;
            l_run *= alpha;
            float aO[4];
#pragma unroll
            for (int jj = 0; jj < 4; jj++) aO[jj] = __shfl(alpha, l4 * 4 + jj);
#pragma unroll
            for (int f = 0; f < 4; f++)
#pragma unroll
                for (int jj = 0; jj < 4; jj++) o[f][jj] *= aO[jj];
        }

        // ---- P = exp2(S - m), mask-zero, l partial, pack, store ----
        float ps = 0.f;
#pragma unroll
        for (int f = 0; f < 4; f++) {
            const uint32_t mword = (f < 2) ? mlo : mhi;
            const int mb = (f & 1) * 16;
            bf16x4 pk;
#pragma unroll
            for (int jj = 0; jj < 4; jj++) {
                float e = fexp2(sf[f][jj] - m_run);
                e = ((mword >> (mb + jj)) & 1u) ? e : 0.f;
                ps += e;
                pk[jj] = (__bf16)e;
            }
            const int off = (f == 0) ? pw0 : (f == 1) ? pw1 : (f == 2) ? pw2 : pw3;
            *(bf16x4*)(ps2row + off) = pk;
        }
        l_run += ps;

        // ---- write next V tile into buf^1 (loads have had QK+softmax to land)
        if (t < NT - 1) storeV(Vt32[nx], kpi, d0, nv0, nv1);

        __builtin_amdgcn_sched_barrier(0);
        const bf16x8 pa0 = *(const bf16x8*)(ps2row + pr0);
        const bf16x8 pa1 = *(const bf16x8*)(ps2row + pr1);

        // ---- O += P V (on buf cur) ----
        const uint32_t* vbase = &Vt32[cur][0][0];
        __builtin_amdgcn_s_setprio(1);
#pragma unroll
        for (int f = 0; f < 4; f++) {
            const bf16x8 bv0 = __builtin_bit_cast(bf16x8, *(const u32x4*)(vbase + f * 512 + vread0));
            const bf16x8 bv1 = __builtin_bit_cast(bf16x8, *(const u32x4*)(vbase + f * 512 + vread1));
            o[f] = __builtin_amdgcn_mfma_f32_16x16x32_bf16(pa0, bv0, o[f], 0, 0, 0);
            o[f] = __builtin_amdgcn_mfma_f32_16x16x32_bf16(pa1, bv1, o[f], 0, 0, 0);
        }
        __builtin_amdgcn_s_setprio(0);

        __syncthreads();   // one barrier per tile
        cur = nx;
    }

    // epilogue: merge l across l4-groups, redistribute, write bf16
    const int b = bh >> 4, h = bh & 15;
    float s = l_run;
    s += __shfl_xor(s, 16);
    s += __shfl_xor(s, 32);
    const float inv = 1.0f / fmaxf(s, 1e-30f);
#pragma unroll
    for (int jj = 0; jj < 4; jj++) {
        const float invj = __shfl(inv, l4 * 4 + jj);
        const int l = q0 + l4 * 4 + jj;
#pragma unroll
        for (int f = 0; f < 4; f++)
            Oout[((size_t)b * LSEQ + l) * DMODEL + h * HDIM + f * 16 + l15] =
                (__bf16)(o[f][jj] * invj);
    }
}

// ---------------------------------------------------------------------------
extern "C" void kernel_launch(void* const* d_in, const int* in_sizes, int n_in,
                              void* d_out, int out_size, void* d_ws, size_t ws_size,
                              hipStream_t stream) {
    const float* x  = (const float*)d_in[0];
    const int* mask = (const int*)d_in[1];
    const float* Wq = (const float*)d_in[2];
    const float* bq = (const float*)d_in[3];
    const float* Wk = (const float*)d_in[4];
    const float* bk = (const float*)d_in[5];
    const float* Wv = (const float*)d_in[6];
    const float* bv = (const float*)d_in[7];
    const float* Wo = (const float*)d_in[8];
    const float* bo = (const float*)d_in[9];

    char* ws = (char*)d_ws;
    __bf16* xb  = (__bf16*)(ws);                    // 16 MiB  [8192][1024]
    __bf16* wqb = (__bf16*)(ws + (16u << 20));      // 2 MiB each; wq|wk|wv|wo contiguous
    __bf16* wob = (__bf16*)(ws + (22u << 20));
    __bf16* qb  = (__bf16*)(ws + (24u << 20));      // q|k|v contiguous, 16 MiB each
    __bf16* ab  = (__bf16*)(ws + (72u << 20));      // 16 MiB  [b][l][1024]
    unsigned long long* mb = (unsigned long long*)(ws + (88u << 20));  // 512 KiB
    float* bqkv = (float*)(ws + (89u << 20));       // 12 KiB packed biases

    const __bf16* kb = qb + ((size_t)1 << 23);
    const __bf16* vb = qb + ((size_t)2 << 23);

    const int M = NBATCH * LSEQ;   // 8192
    const int N = DMODEL;          // 1024
    const int K = DMODEL;          // 1024
    const float cs = 0.18033688011112f;   // 0.125 * log2(e), folded into Q

    cvt_f32_bf16<<<2048, 256, 0, stream>>>(x, xb, M * K);
    cvt_w4<<<4096, 256, 0, stream>>>(Wq, Wk, Wv, Wo, wqb);
    pack_bias<<<12, 256, 0, stream>>>(bq, bk, bv, bqkv);
    pack_mask<<<LSEQ, 256, 0, stream>>>(mask, mb);

    // merged QKV projection: N = 3072 (wq|wk|wv rows are contiguous)
    gemm_bt<0><<<(M / 128) * (3 * N / 128), 256, 0, stream>>>(
        xb, wqb, bqkv, (void*)qb, M, 3 * N, K, cs);

    attn_fwd<<<(LSEQ / 64) * 64, 256, 0, stream>>>(qb, kb, vb, mb, ab);

    gemm_bt<1><<<(M / 128) * (N / 128), 256, 0, stream>>>(
        ab, wob, bo, d_out, M, N, K, 1.0f);
}

// Round 8
// 252.138 us; speedup vs baseline: 1.8696x; 1.0981x over previous
//
#include <hip/hip_runtime.h>
#include <stdint.h>

#define LSEQ 2048
#define DMODEL 1024
#define NHEADS 16
#define HDIM 64
#define NBATCH 4

typedef __attribute__((ext_vector_type(8))) __bf16 bf16x8;
typedef __attribute__((ext_vector_type(4))) __bf16 bf16x4;
typedef __attribute__((ext_vector_type(4))) float f32x4;
typedef __attribute__((ext_vector_type(4))) uint32_t u32x4;
typedef __attribute__((ext_vector_type(4))) uint16_t u16x4;

__device__ inline float fexp2(float x) {
#if __has_builtin(__builtin_amdgcn_exp2f)
    return __builtin_amdgcn_exp2f(x);
#else
    float r; asm("v_exp_f32 %0, %1" : "=v"(r) : "v"(x)); return r;
#endif
}

// ---------------------------------------------------------------------------
// async global->LDS 16B copy (LDS dest = wave-uniform base + lane*16)
// ---------------------------------------------------------------------------
__device__ inline void gload_lds16(const void* g, const void* l) {
    auto gp = reinterpret_cast<const uint32_t __attribute__((address_space(1)))*>(
        reinterpret_cast<uintptr_t>(g));
    auto lp = reinterpret_cast<uint32_t __attribute__((address_space(3)))*>(
        (uint32_t)(uintptr_t)(l));
    __builtin_amdgcn_global_load_lds(gp, lp, 16, 0, 0);
}

// ---------------------------------------------------------------------------
// fp32 -> bf16 convert (vectorized); x activations
// ---------------------------------------------------------------------------
__global__ void cvt_f32_bf16(const float* __restrict__ src, __bf16* __restrict__ dst, int n) {
    int idx = blockIdx.x * blockDim.x + threadIdx.x;
    int stride = gridDim.x * blockDim.x;
    for (int i = idx * 4; i < n; i += stride * 4) {
        float4 f = *(const float4*)(src + i);
        bf16x4 v;
        v[0] = (__bf16)f.x; v[1] = (__bf16)f.y; v[2] = (__bf16)f.z; v[3] = (__bf16)f.w;
        *(bf16x4*)(dst + i) = v;
    }
}

// all 4 weight matrices (1M fp32 each) -> one contiguous bf16 region
__global__ void cvt_w4(const float* __restrict__ a, const float* __restrict__ b,
                       const float* __restrict__ c, const float* __restrict__ d,
                       __bf16* __restrict__ dst) {
    const int t = blockIdx.x * blockDim.x + threadIdx.x;   // 0..1048575
    const int i4 = t * 4;
    const int m = i4 >> 20;
    const int off = i4 & ((1 << 20) - 1);
    const float* src = (m == 0) ? a : (m == 1) ? b : (m == 2) ? c : d;
    float4 f = *(const float4*)(src + off);
    bf16x4 v;
    v[0] = (__bf16)f.x; v[1] = (__bf16)f.y; v[2] = (__bf16)f.z; v[3] = (__bf16)f.w;
    *(bf16x4*)(dst + i4) = v;
}

__global__ void pack_bias(const float* __restrict__ bq, const float* __restrict__ bk,
                          const float* __restrict__ bv, float* __restrict__ dst) {
    const int i = blockIdx.x * 256 + threadIdx.x;   // grid 12 x 256 = 3072
    dst[i] = (i < 1024) ? bq[i] : (i < 2048) ? bk[i - 1024] : bv[i - 2048];
}

// ---------------------------------------------------------------------------
// mask bit-pack: int32 [2048][2048] -> uint64 [2048][32] via __ballot
// ---------------------------------------------------------------------------
__global__ void pack_mask(const int* __restrict__ mask, unsigned long long* __restrict__ mbits) {
    const int row = blockIdx.x;
    const int w = threadIdx.x >> 6, lane = threadIdx.x & 63;
    const int* mrow = mask + (size_t)row * LSEQ;
#pragma unroll
    for (int it = 0; it < 8; it++) {
        const int c = it * 256 + w * 64 + lane;
        const unsigned long long b = __ballot(mrow[c] != 0);
        if (lane == 0) mbits[(size_t)row * 32 + it * 4 + w] = b;
    }
}

// ---------------------------------------------------------------------------
// GEMM: C[m][n] = sum_k A[m][k]*Bw[n][k] + bias[n]   (both row-major, NT)
// 128x128 tile, BK=32, 4 waves (2x2), mfma_f32_16x16x32_bf16, m97 structure.
// XCD-aware blockIdx swizzle (grid % 8 == 0 for all our launches).
// MODE 0: merged-QKV epilogue (N=3072); MODE 1: fp32 row-major
// ---------------------------------------------------------------------------
template <int MODE>
__global__ __launch_bounds__(256) void gemm_bt(const __bf16* __restrict__ A,
                                               const __bf16* __restrict__ Bw,
                                               const float* __restrict__ bias,
                                               void* __restrict__ Cout,
                                               int M, int N, int K, float scale) {
    __shared__ __bf16 As[128 * 32];
    __shared__ __bf16 Bs[128 * 32];

    const int nwg = gridDim.x;
    int bid = blockIdx.x;
    bid = (bid & 7) * (nwg >> 3) + (bid >> 3);   // XCD-chunked swizzle (T1)

    const int nbn = N >> 7;
    const int bm = (bid / nbn) << 7;
    const int bn = (bid % nbn) << 7;
    const int tid = threadIdx.x;
    const int w = tid >> 6, lane = tid & 63;
    const int l15 = lane & 15, l4 = lane >> 4;
    const int wm = (w >> 1) * 64, wn = (w & 1) * 64;

    f32x4 acc[4][4];
    for (int i = 0; i < 4; i++)
        for (int j = 0; j < 4; j++)
            acc[i][j] = (f32x4){0.f, 0.f, 0.f, 0.f};

    const int fa0 = (w * 2 + 0) * 64 + lane;
    const int fa1 = (w * 2 + 1) * 64 + lane;
    const __bf16* gA0 = A + (size_t)(bm + (fa0 >> 2)) * K + (fa0 & 3) * 8;
    const __bf16* gA1 = A + (size_t)(bm + (fa1 >> 2)) * K + (fa1 & 3) * 8;
    const __bf16* gB0 = Bw + (size_t)(bn + (fa0 >> 2)) * K + (fa0 & 3) * 8;
    const __bf16* gB1 = Bw + (size_t)(bn + (fa1 >> 2)) * K + (fa1 & 3) * 8;
    const __bf16* lA0 = &As[(w * 2 + 0) * 512];
    const __bf16* lA1 = &As[(w * 2 + 1) * 512];
    const __bf16* lB0 = &Bs[(w * 2 + 0) * 512];
    const __bf16* lB1 = &Bs[(w * 2 + 1) * 512];

    for (int kt = 0; kt < K; kt += 32) {
        __syncthreads();
        gload_lds16(gA0 + kt, lA0);
        gload_lds16(gA1 + kt, lA1);
        gload_lds16(gB0 + kt, lB0);
        gload_lds16(gB1 + kt, lB1);
        __syncthreads();

        bf16x8 af[4], bw[4];
        for (int i = 0; i < 4; i++)
            af[i] = *(const bf16x8*)&As[(wm + i * 16 + l15) * 32 + l4 * 8];
        for (int j = 0; j < 4; j++)
            bw[j] = *(const bf16x8*)&Bs[(wn + j * 16 + l15) * 32 + l4 * 8];
        for (int i = 0; i < 4; i++)
            for (int j = 0; j < 4; j++)
                acc[i][j] = __builtin_amdgcn_mfma_f32_16x16x32_bf16(af[i], bw[j], acc[i][j], 0, 0, 0);
    }

    for (int i = 0; i < 4; i++) {
        const int row0 = bm + wm + i * 16 + l4 * 4;
        for (int j = 0; j < 4; j++) {
            const int col = bn + wn + j * 16 + l15;
            const float bv = bias[col];
            if (MODE == 0) {
                __bf16* dst = (__bf16*)Cout;
                const int which = col >> 10;
                const int cr = col & 1023;
                const int h = cr >> 6, d = cr & 63;
                const float scl = (which == 0) ? scale : 1.0f;
                for (int jj = 0; jj < 4; jj++) {
                    const int r = row0 + jj;
                    const int b = r >> 11, l = r & (LSEQ - 1);
                    dst[((size_t)which << 23) +
                        (((size_t)(b * NHEADS + h) * LSEQ + l) << 6) + d] =
                        (__bf16)((acc[i][j][jj] + bv) * scl);
                }
            } else {
                float* dst = (float*)Cout;
                for (int jj = 0; jj < 4; jj++) {
                    const int r = row0 + jj;
                    dst[(size_t)r * N + col] = acc[i][j][jj] + bv;
                }
            }
        }
    }
}

// ---------------------------------------------------------------------------
// V store helper: k-pair transposed layout, 4 d-values per thread.
// Vt32[d][col] with col = (kp&3) | (((kp>>2) ^ (d&7)) << 2)
// ---------------------------------------------------------------------------
__device__ inline void storeV4(uint32_t (*vt)[32], int kpi, int d0,
                               const u16x4& r0, const u16x4& r1) {
    const uint32_t* a = (const uint32_t*)&r0;
    const uint32_t* b = (const uint32_t*)&r1;
#pragma unroll
    for (int jp = 0; jp < 2; jp++) {
        const uint32_t w0 = __builtin_amdgcn_perm(b[jp], a[jp], 0x05040100u);
        const uint32_t w1 = __builtin_amdgcn_perm(b[jp], a[jp], 0x07060302u);
        const int da = d0 + jp * 2, db = da + 1;
        vt[da][(kpi & 3) | (((kpi >> 2) ^ (da & 7)) << 2)] = w0;
        vt[db][(kpi & 3) | (((kpi >> 2) ^ (db & 7)) << 2)] = w1;
    }
}

// ---------------------------------------------------------------------------
// Flash attention, swapped QK^T, 8 waves x 16 q-rows (QBLK=128), KVBLK=64.
// Single-barrier double-buffered staging; K/V staging amortized over 2x the
// q-rows vs QBLK=64. LDS = 16K(Ks dbuf) + 16K(Vt dbuf) + 16K(Ps2) = 48K ->
// 3 blocks x 512 thr = 24 waves/CU.
// ---------------------------------------------------------------------------
__global__ __launch_bounds__(512) void attn_fwd(const __bf16* __restrict__ Q,
                                                const __bf16* __restrict__ Kk,
                                                const __bf16* __restrict__ V,
                                                const unsigned long long* __restrict__ mbits,
                                                __bf16* __restrict__ Oout) {
    const int bh = blockIdx.x & 63;
    const int qt = blockIdx.x >> 6;
    const int tid = threadIdx.x;
    const int w = tid >> 6, lane = tid & 63;
    const int l15 = lane & 15, l4 = lane >> 4, l7 = l15 & 7;

    __shared__ __bf16 Ks[2][64 * 64];     // dbuf; row-major, 16B-chunk XOR swizzle
    __shared__ uint32_t Vt32[2][64][32];  // dbuf; [d][kpair], block-XOR swizzled
    __shared__ __bf16 Ps2[8][16][64];     // per-wave P tile; 128B rows (XOR swz)

    const int q0 = qt * 128 + w * 16;
    const __bf16* qbase = Q + ((size_t)bh * LSEQ + q0 + l15) * HDIM + l4 * 8;
    const bf16x8 aq0 = *(const bf16x8*)(qbase);
    const bf16x8 aq1 = *(const bf16x8*)(qbase + 32);

    f32x4 o[4];
    for (int f = 0; f < 4; f++) o[f] = (f32x4){0.f, 0.f, 0.f, 0.f};
    float m_run = -1.0e30f, l_run = 0.f;

    // ---- K staging: 512 chunks of 16B, one per thread ----
    const int ck = tid;
    const int koff = ((ck >> 3) << 7) + ((((ck & 7) ^ ((ck >> 3) & 7))) << 4);
    const char* kp0 = (const char*)(Kk + (size_t)bh * LSEQ * HDIM) + koff;
    const int kdst = tid * 8;           // element offset within Ks[x]

    // K fragment read (byte) addrs: row*128 + 16*((ks*4+l4)^l7), row = f*16+l15
    const int kread0 = l15 * 128 + ((l4 ^ l7) << 4);
    const int kread1 = l15 * 128 + (((4 + l4) ^ l7) << 4);
    // V fragment read (word) addrs: row*32 + 4*((ks*4+l4)^l7), row = f*16+l15
    const int vread0 = l15 * 32 + ((l4 ^ l7) << 2);
    const int vread1 = l15 * 32 + (((4 + l4) ^ l7) << 2);

    // V staging: thread -> k-pair kpi (rows 2kpi,2kpi+1), d-chunk d0..d0+3
    const int kpi = tid & 31;
    const int d0 = (tid >> 5) * 4;
    const __bf16* vp0 = V + (size_t)bh * LSEQ * HDIM + (size_t)(2 * kpi) * HDIM + d0;
    const __bf16* vp1 = vp0 + HDIM;

    // Ps2 addressing: per-wave q-row l15, byte XOR swizzle (row stride 128B)
    char* ps2row = (char*)&Ps2[w][l15][0];
    const int xr = (l15 & 3) << 5;
    const int pw0 = (0 * 32 + l4 * 8) ^ xr;
    const int pw1 = (1 * 32 + l4 * 8) ^ xr;
    const int pw2 = (2 * 32 + l4 * 8) ^ xr;
    const int pw3 = (3 * 32 + l4 * 8) ^ xr;
    const int pr0 = (0 * 64 + l4 * 16) ^ xr;
    const int pr1 = (1 * 64 + l4 * 16) ^ xr;

    // mask: lane's q-row word stream (one uint2 per 64-col tile)
    const uint2* mptr = (const uint2*)(mbits + (size_t)(q0 + l15) * 32);
    const int sh4 = l4 * 4;

    // ---- prologue: stage tile 0 into buffer 0 ----
    {
        const u16x4 v0 = *(const u16x4*)(vp0);
        const u16x4 v1 = *(const u16x4*)(vp1);
        vp0 += 64 * HDIM; vp1 += 64 * HDIM;
        gload_lds16(kp0, &Ks[0][kdst]);
        kp0 += 8192;
        storeV4(Vt32[0], kpi, d0, v0, v1);
    }
    __syncthreads();

    int cur = 0;
    const int NT = LSEQ / 64;   // 32
    for (int t = 0; t < NT; t++) {
        const int nx = cur ^ 1;
        u16x4 nv0, nv1;
        if (t < NT - 1) {
            nv0 = *(const u16x4*)(vp0);
            nv1 = *(const u16x4*)(vp1);
            vp0 += 64 * HDIM; vp1 += 64 * HDIM;
            gload_lds16(kp0, &Ks[nx][kdst]);
            kp0 += 8192;
        }

        const uint2 mw = mptr[t];
        const uint32_t mlo = mw.x >> sh4;
        const uint32_t mhi = mw.y >> sh4;

        // ---- S^T = K Q^T : lane holds S[k=f*16+l4*4+jj][q=l15] ----
        const char* ksb = (const char*)&Ks[cur][0];
        f32x4 sf[4];
        __builtin_amdgcn_s_setprio(1);
#pragma unroll
        for (int f = 0; f < 4; f++) {
            const bf16x8 bk0 = *(const bf16x8*)(ksb + f * 2048 + kread0);
            const bf16x8 bk1 = *(const bf16x8*)(ksb + f * 2048 + kread1);
            f32x4 z = (f32x4){0.f, 0.f, 0.f, 0.f};
            z = __builtin_amdgcn_mfma_f32_16x16x32_bf16(bk0, aq0, z, 0, 0, 0);
            z = __builtin_amdgcn_mfma_f32_16x16x32_bf16(bk1, aq1, z, 0, 0, 0);
            sf[f] = z;
        }
        __builtin_amdgcn_s_setprio(0);

        // ---- lane-local max + 2-shfl merge ----
        float vmx;
        {
            float a0 = fmaxf(fmaxf(sf[0][0], sf[0][1]), fmaxf(sf[0][2], sf[0][3]));
            float a1 = fmaxf(fmaxf(sf[1][0], sf[1][1]), fmaxf(sf[1][2], sf[1][3]));
            float a2 = fmaxf(fmaxf(sf[2][0], sf[2][1]), fmaxf(sf[2][2], sf[2][3]));
            float a3 = fmaxf(fmaxf(sf[3][0], sf[3][1]), fmaxf(sf[3][2], sf[3][3]));
            vmx = fmaxf(fmaxf(a0, a1), fmaxf(a2, a3));
            vmx = fmaxf(vmx, __shfl_xor(vmx, 16));
            vmx = fmaxf(vmx, __shfl_xor(vmx, 32));
        }

        // ---- defer-max ----
        if (__any(vmx > m_run + 8.f)) {
            const float mnew = fmaxf(m_run, vmx);
            const float alpha = fexp2(m_run - mnew);
            m_run = mnew;
            l_run *= alpha;
            float aO[4];
#pragma unroll
            for (int jj = 0; jj < 4; jj++) aO[jj] = __shfl(alpha, l4 * 4 + jj);
#pragma unroll
            for (int f = 0; f < 4; f++)
#pragma unroll
                for (int jj = 0; jj < 4; jj++) o[f][jj] *= aO[jj];
        }

        // ---- P = exp2(S - m), mask-zero, l partial, pack, store ----
        float ps = 0.f;
#pragma unroll
        for (int f = 0; f < 4; f++) {
            const uint32_t mword = (f < 2) ? mlo : mhi;
            const int mb = (f & 1) * 16;
            bf16x4 pk;
#pragma unroll
            for (int jj = 0; jj < 4; jj++) {
                float e = fexp2(sf[f][jj] - m_run);
                e = ((mword >> (mb + jj)) & 1u) ? e : 0.f;
                ps += e;
                pk[jj] = (__bf16)e;
            }
            const int off = (f == 0) ? pw0 : (f == 1) ? pw1 : (f == 2) ? pw2 : pw3;
            *(bf16x4*)(ps2row + off) = pk;
        }
        l_run += ps;

        // ---- write next V tile into buf^1 ----
        if (t < NT - 1) storeV4(Vt32[nx], kpi, d0, nv0, nv1);

        __builtin_amdgcn_sched_barrier(0);
        const bf16x8 pa0 = *(const bf16x8*)(ps2row + pr0);
        const bf16x8 pa1 = *(const bf16x8*)(ps2row + pr1);

        // ---- O += P V (on buf cur) ----
        const uint32_t* vbase = &Vt32[cur][0][0];
        __builtin_amdgcn_s_setprio(1);
#pragma unroll
        for (int f = 0; f < 4; f++) {
            const bf16x8 bv0 = __builtin_bit_cast(bf16x8, *(const u32x4*)(vbase + f * 512 + vread0));
            const bf16x8 bv1 = __builtin_bit_cast(bf16x8, *(const u32x4*)(vbase + f * 512 + vread1));
            o[f] = __builtin_amdgcn_mfma_f32_16x16x32_bf16(pa0, bv0, o[f], 0, 0, 0);
            o[f] = __builtin_amdgcn_mfma_f32_16x16x32_bf16(pa1, bv1, o[f], 0, 0, 0);
        }
        __builtin_amdgcn_s_setprio(0);

        __syncthreads();   // one barrier per tile
        cur = nx;
    }

    // epilogue: merge l across l4-groups, redistribute, write bf16
    const int b = bh >> 4, h = bh & 15;
    float s = l_run;
    s += __shfl_xor(s, 16);
    s += __shfl_xor(s, 32);
    const float inv = 1.0f / fmaxf(s, 1e-30f);
#pragma unroll
    for (int jj = 0; jj < 4; jj++) {
        const float invj = __shfl(inv, l4 * 4 + jj);
        const int l = q0 + l4 * 4 + jj;
#pragma unroll
        for (int f = 0; f < 4; f++)
            Oout[((size_t)b * LSEQ + l) * DMODEL + h * HDIM + f * 16 + l15] =
                (__bf16)(o[f][jj] * invj);
    }
}

// ---------------------------------------------------------------------------
extern "C" void kernel_launch(void* const* d_in, const int* in_sizes, int n_in,
                              void* d_out, int out_size, void* d_ws, size_t ws_size,
                              hipStream_t stream) {
    const float* x  = (const float*)d_in[0];
    const int* mask = (const int*)d_in[1];
    const float* Wq = (const float*)d_in[2];
    const float* bq = (const float*)d_in[3];
    const float* Wk = (const float*)d_in[4];
    const float* bk = (const float*)d_in[5];
    const float* Wv = (const float*)d_in[6];
    const float* bv = (const float*)d_in[7];
    const float* Wo = (const float*)d_in[8];
    const float* bo = (const float*)d_in[9];

    char* ws = (char*)d_ws;
    __bf16* xb  = (__bf16*)(ws);                    // 16 MiB  [8192][1024]
    __bf16* wqb = (__bf16*)(ws + (16u << 20));      // 2 MiB each; wq|wk|wv|wo contiguous
    __bf16* wob = (__bf16*)(ws + (22u << 20));
    __bf16* qb  = (__bf16*)(ws + (24u << 20));      // q|k|v contiguous, 16 MiB each
    __bf16* ab  = (__bf16*)(ws + (72u << 20));      // 16 MiB  [b][l][1024]
    unsigned long long* mb = (unsigned long long*)(ws + (88u << 20));  // 512 KiB
    float* bqkv = (float*)(ws + (89u << 20));       // 12 KiB packed biases

    const __bf16* kb = qb + ((size_t)1 << 23);
    const __bf16* vb = qb + ((size_t)2 << 23);

    const int M = NBATCH * LSEQ;   // 8192
    const int N = DMODEL;          // 1024
    const int K = DMODEL;          // 1024
    const float cs = 0.18033688011112f;   // 0.125 * log2(e), folded into Q

    cvt_f32_bf16<<<2048, 256, 0, stream>>>(x, xb, M * K);
    cvt_w4<<<4096, 256, 0, stream>>>(Wq, Wk, Wv, Wo, wqb);
    pack_bias<<<12, 256, 0, stream>>>(bq, bk, bv, bqkv);
    pack_mask<<<LSEQ, 256, 0, stream>>>(mask, mb);

    // merged QKV projection: N = 3072 (wq|wk|wv rows are contiguous)
    gemm_bt<0><<<(M / 128) * (3 * N / 128), 256, 0, stream>>>(
        xb, wqb, bqkv, (void*)qb, M, 3 * N, K, cs);

    attn_fwd<<<(LSEQ / 128) * 64, 512, 0, stream>>>(qb, kb, vb, mb, ab);

    gemm_bt<1><<<(M / 128) * (N / 128), 256, 0, stream>>>(
        ab, wob, bo, d_out, M, N, K, 1.0f);
}